// Round 2
// baseline (27763.388 us; speedup 1.0000x reference)
//
#include <hip/hip_runtime.h>
#include <hip/hip_bf16.h>

typedef unsigned short u16;
typedef unsigned int u32;
typedef __attribute__((ext_vector_type(8))) short short8;
typedef __attribute__((ext_vector_type(8))) u16 ushort8;
typedef __attribute__((ext_vector_type(4))) float f32x4;
typedef __attribute__((ext_vector_type(4))) u32 u32x4;

__device__ __forceinline__ float bf2f(u16 x){ u32 u=((u32)x)<<16; return __builtin_bit_cast(float,u); }
__device__ __forceinline__ u16 f2bf(float f){ u32 u=__builtin_bit_cast(u32,f); u32 r=(u+0x7fffu+((u>>16)&1u))>>16; return (u16)r; }
__device__ __forceinline__ float sigf(float x){ return 1.f/(1.f+__expf(-x)); }

// ---------------- prologue kernels ----------------

__global__ __launch_bounds__(256) void k_cast(const float* __restrict__ s, u16* __restrict__ d, long n){
  long i = ((long)blockIdx.x*256 + threadIdx.x)*8;
  if (i >= n) return;
  float4 a = *(const float4*)(s+i);
  float4 b = *(const float4*)(s+i+4);
  ushort8 o;
  o[0]=f2bf(a.x); o[1]=f2bf(a.y); o[2]=f2bf(a.z); o[3]=f2bf(a.w);
  o[4]=f2bf(b.x); o[5]=f2bf(b.y); o[6]=f2bf(b.z); o[7]=f2bf(b.w);
  *(ushort8*)(d+i) = o;
}

// WC[j][0:2816] = [W_ih[j][0:1792] | W_hh[j][0:1024]]  (bf16)
__global__ __launch_bounds__(256) void k_build_wc(const float* __restrict__ Wih, const float* __restrict__ Whh,
                                                  u16* __restrict__ WC){
  long i8 = (long)blockIdx.x*256 + threadIdx.x;           // 4096*352
  if (i8 >= (long)4096*352) return;
  int j = (int)(i8/352); int kk = (int)(i8%352)*8;
  const float* src = (kk < 1792) ? (Wih + (long)j*1792 + kk) : (Whh + (long)j*1024 + (kk-1792));
  u16* dst = WC + (long)j*2816 + kk;
  ushort8 o;
  #pragma unroll
  for (int q=0;q<8;++q) o[q] = f2bf(src[q]);
  *(ushort8*)dst = o;
}

// W_attT[m][k] = W_att[k][m]  (bf16)
__global__ __launch_bounds__(256) void k_wattT(const float* __restrict__ Wa, u16* __restrict__ WT){
  int id = blockIdx.x*256 + threadIdx.x;                  // 1M
  int m = id >> 10, k = id & 1023;
  WT[(long)m*1024 + k] = f2bf(Wa[(long)k*1024 + m]);
}

// mean over S -> bf16 [64][1024]; grid (64,4)
__global__ __launch_bounds__(256) void k_mean(const u16* __restrict__ ENC, u16* __restrict__ MEANB){
  int b = blockIdx.x, h = blockIdx.y*256 + threadIdx.x;
  const u16* p = ENC + ((long)b<<20) + h;
  float s = 0.f;
  for (int ss=0; ss<1024; ++ss) s += bf2f(p[(long)ss<<10]);
  MEANB[b*1024 + h] = f2bf(s * (1.f/1024.f));
}

// a_e / t_e slots of XC for all t  (zeros where !prev_valid)
__global__ __launch_bounds__(256) void k_embed(const float* __restrict__ pemb, const float* __restrict__ temb,
      const int* __restrict__ pid, const int* __restrict__ tid_, const int* __restrict__ slen,
      u16* __restrict__ XC){
  int t = blockIdx.x >> 6, b = blockIdx.x & 63;
  bool valid = (t>0) && (t < slen[b]);
  int pi = pid[b*64 + t], ti = tid_[b*64 + t];
  u16* dst = XC + (long)blockIdx.x*2816;
  for (int kk = threadIdx.x; kk < 768; kk += 256){
    float v = 0.f;
    if (valid) v = (kk<512) ? pemb[(long)pi*512 + kk] : temb[(long)ti*256 + (kk-512)];
    dst[(kk<512) ? kk : (1024+kk)] = f2bf(v);
  }
}

// generic small GEMM: out = A[M x K] @ W[N x K]^T (block: 64 rows x 16 cols, 4 waves)
// MODE 2: tanh(+bias)->bf16   3: +bias -> f32
template<int MODE>
__global__ __launch_bounds__(256) void k_gemm(const u16* __restrict__ A, long lda,
      const u16* __restrict__ W, int K, const float* __restrict__ bias,
      float* __restrict__ OF, long ldo, u16* __restrict__ OB1, long ldb1){
  int l = threadIdx.x & 63, w = threadIdx.x >> 6;
  int c = l & 15, g = l >> 4;
  int n0 = blockIdx.x*16, m0 = blockIdx.y*64;
  const u16* ap = A + (long)(m0 + w*16 + c)*lda + g*8;
  const u16* bp = W + (long)(n0 + c)*K + g*8;
  f32x4 acc = {0.f,0.f,0.f,0.f};
  int kit = K >> 5;
  #pragma unroll 4
  for (int kb=0; kb<kit; ++kb){
    short8 av = *(const short8*)(ap + kb*32);
    short8 bv = *(const short8*)(bp + kb*32);
    acc = __builtin_amdgcn_mfma_f32_16x16x32_bf16(av, bv, acc, 0, 0, 0);
  }
  #pragma unroll
  for (int r=0;r<4;++r){
    int row = m0 + w*16 + g*4 + r;
    int col = n0 + c;
    float v = acc[r];
    if (MODE==2){ OB1[(long)row*ldb1 + col] = f2bf(tanhf(v + bias[col])); }
    if (MODE==3){ OF[(long)row*ldo + col] = v + bias[col]; }
  }
}

// per-b deterministic loss accumulation
__global__ __launch_bounds__(256) void k_loss(const float* __restrict__ LG, const int* __restrict__ tgt,
      const int* __restrict__ slen, float* __restrict__ out){
  int b = blockIdx.x;
  int w = threadIdx.x >> 6, l = threadIdx.x & 63;
  int len = slen[b];
  float accum = 0.f;
  for (int t = w; t < 64; t += 4){
    if (t >= len) continue;
    const float* lp = LG + ((long)(t*64 + b))*256;
    float v0=lp[l], v1=lp[l+64], v2=lp[l+128], v3=lp[l+192];
    float mx = fmaxf(fmaxf(v0,v1), fmaxf(v2,v3));
    #pragma unroll
    for (int off=32; off; off>>=1) mx = fmaxf(mx, __shfl_xor(mx, off));
    float s = __expf(v0-mx)+__expf(v1-mx)+__expf(v2-mx)+__expf(v3-mx);
    #pragma unroll
    for (int off=32; off; off>>=1) s += __shfl_xor(s, off);
    float ltg = lp[tgt[b*64 + t]];
    float p = __expf(ltg - mx)/s;
    accum += logf(p + 1e-8f);
  }
  __shared__ float sm[4];
  if (l == 0) sm[w] = accum;
  __syncthreads();
  if (threadIdx.x == 0) out[b] = sm[0]+sm[1]+sm[2]+sm[3];
}

// ---------------- persistent decoder ----------------

__device__ __forceinline__ void grid_sync(int* __restrict__ bar, int nb, int& bargen){
  bargen += 1;
  __threadfence();
  __syncthreads();
  if (threadIdx.x == 0){
    int* cnt = bar;
    int* gen = bar + 64;
    int prev = __hip_atomic_fetch_add(cnt, 1, __ATOMIC_ACQ_REL, __HIP_MEMORY_SCOPE_AGENT);
    if (prev == nb-1){
      __hip_atomic_store(cnt, 0, __ATOMIC_RELAXED, __HIP_MEMORY_SCOPE_AGENT);
      __hip_atomic_store(gen, bargen, __ATOMIC_RELEASE, __HIP_MEMORY_SCOPE_AGENT);
    } else {
      while (__hip_atomic_load(gen, __ATOMIC_ACQUIRE, __HIP_MEMORY_SCOPE_AGENT) < bargen){
        __builtin_amdgcn_s_sleep(2);
      }
    }
  }
  __syncthreads();
  __threadfence();
}

__global__ __launch_bounds__(512,2) void k_decoder(
      const u16* __restrict__ ENC, const u16* __restrict__ WC,
      const u16* __restrict__ WAVT, const u16* __restrict__ WAVEC,
      const float* __restrict__ bih, const float* __restrict__ bhh,
      u16* __restrict__ XC, u16* __restrict__ ATT,
      float* __restrict__ HW, float* __restrict__ PM, float* __restrict__ PL,
      float* __restrict__ CTXP, const int* __restrict__ src_lens,
      int* __restrict__ BAR){
  const int tid = threadIdx.x;
  const int w = tid >> 6, l = tid & 63, c = l & 15, g = l >> 4;
  const int bx = blockIdx.x;
  int bargen = 0;

  __shared__ float smem[10304];                 // 40.25KB, phase-aliased
  f32x4* lacc  = (f32x4*)smem;                  // P1/P2: [8][64] f32x4 (8KB)
  float* s_ctx = smem;                          // P3: [8][1024] (32KB)
  float* s_mx  = smem + 8192;                   // P3: [8]
  float* s_ls  = smem + 8208;                   // P3: [8]
  u16*   ldsc  = (u16*)smem;                    // P4: [16][1024] bf16 (32KB)
  f32x4* lacc4 = (f32x4*)(smem + 8192);         // P4: [8][64] f32x4 (8KB)

  // P1 constants (block = 4 output-n x 4 gates, waves: mt = w&3 (16 b), kh = w>>2)
  const int n0 = bx << 2;
  const int jrow = n0 + (c & 3) + ((c >> 2) << 10);
  const float biasj = bih[jrow] + bhh[jrow];
  const int kh = w >> 2, mt = w & 3;
  const int lbase = l & 0x33;
  float creg[4] = {0.f,0.f,0.f,0.f};
  // P2 constants (block = mtile(16b) x ntile(16 cols); waves = 8 K-chunks of 128)
  const int mt2 = bx & 3, nt2 = bx >> 2;
  // P3 constants (block = b x chunk; 8 waves stride s)
  const int b3 = bx >> 2, p3 = bx & 3;
  int len = src_lens[b3]; if (len < 1) len = 1; if (len > 1024) len = 1024;
  const int chunk = (len + 3) >> 2;
  const int s0 = p3*chunk;
  const int s1 = (s0 + chunk < len) ? (s0 + chunk) : len;
  // P4 constants (block = mtile(16b) x ntile(16 cols); waves = 8 K-chunks of 256)
  const int mt4 = bx & 3, nt4 = bx >> 2;
  const int b16 = tid >> 5, lane32 = tid & 31;

  for (int t = 0; t < 64; ++t){
    const u16* XCt = XC + (size_t)t*64*2816;
    u16* XCn = XC + (size_t)(t+1)*64*2816;
    const u16* Hcur = XCn + 1792;               // h_t, row stride 2816

    // ---- P1: LSTM gates GEMM (split-K x2) + pointwise, h -> XCn ----
    {
      const u16* ap = XCt + (long)(mt*16 + c)*2816 + kh*1408 + g*8;
      const u16* bp = WC  + (long)jrow*2816 + kh*1408 + g*8;
      f32x4 acc = {0.f,0.f,0.f,0.f};
      #pragma unroll 4
      for (int kb=0; kb<44; ++kb){
        short8 av = *(const short8*)(ap + kb*32);
        short8 bv = *(const short8*)(bp + kb*32);
        acc = __builtin_amdgcn_mfma_f32_16x16x32_bf16(av, bv, acc, 0, 0, 0);
      }
      lacc[w*64 + l] = acc;
      __syncthreads();
      if (w < 4){
        f32x4 a0 = lacc[w*64 + l];
        f32x4 a1 = lacc[(w+4)*64 + l];
        #pragma unroll
        for (int r=0;r<4;++r){
          float val = a0[r] + a1[r] + biasj;
          float iv = __shfl(val, lbase);
          float fv = __shfl(val, lbase+4);
          float gv = __shfl(val, lbase+8);
          float ov = __shfl(val, lbase+12);
          if ((l & 12) == 0){
            float cn = sigf(fv)*creg[r] + sigf(iv)*tanhf(gv);
            float hn = sigf(ov)*tanhf(cn);
            creg[r] = cn;
            int b = w*16 + g*4 + r;
            int n = n0 + (l & 3);
            XCn[(long)b*2816 + 1792 + n] = f2bf(hn);
          }
        }
      }
    }
    grid_sync(BAR, 256, bargen);

    // ---- P2: HW = h @ W_att^T  (8-way split-K, LDS reduce) ----
    {
      const u16* ap = Hcur + (long)(mt2*16 + c)*2816 + w*128 + g*8;
      const u16* bp = WAVT + (long)(nt2*16 + c)*1024 + w*128 + g*8;
      f32x4 acc = {0.f,0.f,0.f,0.f};
      #pragma unroll
      for (int kb=0; kb<4; ++kb){
        short8 av = *(const short8*)(ap + kb*32);
        short8 bv = *(const short8*)(bp + kb*32);
        acc = __builtin_amdgcn_mfma_f32_16x16x32_bf16(av, bv, acc, 0, 0, 0);
      }
      lacc[w*64 + l] = acc;
      __syncthreads();
      if (w == 0){
        f32x4 rd = lacc[l];
        #pragma unroll
        for (int w2=1; w2<8; ++w2) rd += lacc[w2*64 + l];
        #pragma unroll
        for (int r=0;r<4;++r)
          HW[(long)(mt2*16 + g*4 + r)*1024 + nt2*16 + c] = rd[r];
      }
    }
    grid_sync(BAR, 256, bargen);

    // ---- P3: attention partials (online softmax over s-chunk, 8 waves) ----
    {
      float hw[16], ctx[16];
      const float* hwp = HW + b3*1024 + l*16;
      #pragma unroll
      for (int jj=0;jj<16;++jj){ hw[jj]=hwp[jj]; ctx[jj]=0.f; }
      float m = -INFINITY, lsum = 0.f;
      for (int s = s0 + w; s < s1; s += 8){
        const u16* ep = ENC + (((long)(b3*1024 + s))<<10) + l*16;
        u32x4 q0 = __builtin_nontemporal_load((const u32x4*)ep);
        u32x4 q1 = __builtin_nontemporal_load(((const u32x4*)ep)+1);
        float e[16];
        #pragma unroll
        for (int jj=0;jj<4;++jj){
          e[2*jj]   = bf2f((u16)(q0[jj]&0xffff));
          e[2*jj+1] = bf2f((u16)(q0[jj]>>16));
          e[8+2*jj]   = bf2f((u16)(q1[jj]&0xffff));
          e[8+2*jj+1] = bf2f((u16)(q1[jj]>>16));
        }
        float sc = 0.f;
        #pragma unroll
        for (int jj=0;jj<16;++jj) sc += e[jj]*hw[jj];
        #pragma unroll
        for (int off=32; off; off>>=1) sc += __shfl_xor(sc, off);
        float nm = fmaxf(m, sc);
        float pe = __expf(sc - nm);
        if (nm > m){
          float corr = __expf(m - nm);
          lsum *= corr;
          #pragma unroll
          for (int jj=0;jj<16;++jj) ctx[jj] *= corr;
          m = nm;
        }
        lsum += pe;
        #pragma unroll
        for (int jj=0;jj<16;++jj) ctx[jj] += pe*e[jj];
      }
      #pragma unroll
      for (int jj=0;jj<16;++jj) s_ctx[w*1024 + l*16 + jj] = ctx[jj];
      if (l == 0){ s_mx[w] = m; s_ls[w] = lsum; }
      __syncthreads();
      float M8 = s_mx[0];
      #pragma unroll
      for (int q=1;q<8;++q) M8 = fmaxf(M8, s_mx[q]);
      float wei[8]; float L = 0.f;
      #pragma unroll
      for (int q=0;q<8;++q){
        wei[q] = (s_mx[q] == -INFINITY) ? 0.f : __expf(s_mx[q]-M8);
        L += wei[q]*s_ls[q];
      }
      #pragma unroll
      for (int q=0;q<2;++q){
        int mm = tid + q*512;
        float v = 0.f;
        #pragma unroll
        for (int p=0;p<8;++p) v += wei[p]*s_ctx[p*1024 + mm];
        CTXP[(long)bx*1024 + mm] = v;
      }
      if (tid == 0){ PM[bx] = M8; PL[bx] = L; }
    }
    grid_sync(BAR, 256, bargen);

    // ---- P4: ctx combine (16 b -> LDS, swizzled) + att = tanh([h|ctx]@W_attvec^T) ----
    {
      int b = mt4*16 + b16;
      float m0=PM[b*4], m1=PM[b*4+1], m2=PM[b*4+2], m3=PM[b*4+3];
      float M = fmaxf(fmaxf(m0,m1), fmaxf(m2,m3));
      float w0 = (m0==-INFINITY)?0.f:__expf(m0-M);
      float w1 = (m1==-INFINITY)?0.f:__expf(m1-M);
      float w2 = (m2==-INFINITY)?0.f:__expf(m2-M);
      float w3 = (m3==-INFINITY)?0.f:__expf(m3-M);
      float L = w0*PL[b*4] + w1*PL[b*4+1] + w2*PL[b*4+2] + w3*PL[b*4+3];
      float inv = (L > 0.f) ? 1.f/L : 0.f;
      const float* c0 = CTXP + (long)(b*4+0)*1024;
      const float* c1 = CTXP + (long)(b*4+1)*1024;
      const float* c2 = CTXP + (long)(b*4+2)*1024;
      const float* c3 = CTXP + (long)(b*4+3)*1024;
      const int swz = (b16 & 7) << 3;
      #pragma unroll 8
      for (int q=0;q<32;++q){
        int mcol = lane32 + q*32;
        float v = (w0*c0[mcol] + w1*c1[mcol] + w2*c2[mcol] + w3*c3[mcol]) * inv;
        ldsc[(b16*1024 + mcol) ^ swz] = f2bf(v);
      }
      __syncthreads();
      f32x4 acc = {0.f,0.f,0.f,0.f};
      const u16* bp = WAVEC + (long)(nt4*16 + c)*2048 + w*256 + g*8;
      if (w < 4){
        const u16* ap = Hcur + (long)(mt4*16 + c)*2816 + w*256 + g*8;
        #pragma unroll
        for (int kb=0; kb<8; ++kb){
          short8 av = *(const short8*)(ap + kb*32);
          short8 bv = *(const short8*)(bp + kb*32);
          acc = __builtin_amdgcn_mfma_f32_16x16x32_bf16(av, bv, acc, 0, 0, 0);
        }
      } else {
        const int cswz = (c & 7) << 3;
        const int kbase = c*1024 + (w-4)*256 + g*8;
        #pragma unroll
        for (int kb=0; kb<8; ++kb){
          short8 av = *(const short8*)(ldsc + ((kbase + kb*32) ^ cswz));
          short8 bv = *(const short8*)(bp + kb*32);
          acc = __builtin_amdgcn_mfma_f32_16x16x32_bf16(av, bv, acc, 0, 0, 0);
        }
      }
      lacc4[w*64 + l] = acc;
      __syncthreads();
      if (w == 0){
        f32x4 rd = lacc4[l];
        #pragma unroll
        for (int w2=1; w2<8; ++w2) rd += lacc4[w2*64 + l];
        #pragma unroll
        for (int r=0;r<4;++r){
          int b_ = mt4*16 + g*4 + r;
          int col = nt4*16 + c;
          u16 x = f2bf(tanhf(rd[r]));
          XCn[(long)b_*2816 + 512 + col] = x;
          ATT[((long)t*64 + b_)*1024 + col] = x;
        }
      }
    }
    grid_sync(BAR, 256, bargen);
  }
}

extern "C" void kernel_launch(void* const* d_in, const int* in_sizes, int n_in,
                              void* d_out, int out_size, void* d_ws, size_t ws_size,
                              hipStream_t stream){
  const float* enc      = (const float*)d_in[0];
  const float* W_ih     = (const float*)d_in[1];
  const float* b_ih     = (const float*)d_in[2];
  const float* W_hh     = (const float*)d_in[3];
  const float* b_hh     = (const float*)d_in[4];
  const float* W_att    = (const float*)d_in[5];
  const float* W_attvec = (const float*)d_in[6];
  const float* W_init   = (const float*)d_in[7];
  const float* b_init   = (const float*)d_in[8];
  const float* W_q2a    = (const float*)d_in[9];
  const float* b_q2a    = (const float*)d_in[10];
  const float* prod_emb = (const float*)d_in[11];
  const float* prod_bias= (const float*)d_in[12];
  const float* type_emb = (const float*)d_in[13];
  const int* prev_pid   = (const int*)d_in[14];
  const int* prev_tid   = (const int*)d_in[15];
  const int* target     = (const int*)d_in[16];
  const int* sk_lens    = (const int*)d_in[17];
  const int* src_lens   = (const int*)d_in[18];
  float* out = (float*)d_out;

  char* ws = (char*)d_ws;
  size_t o = 0;
  auto alloc = [&](size_t bytes)->char*{ char* p = ws + o; o += (bytes + 255) & ~(size_t)255; return p; };
  u16*  ENC  = (u16*)alloc((size_t)64*1024*1024*2);   // 128MB
  u16*  WC   = (u16*)alloc((size_t)4096*2816*2);      // 22.5MB
  u16*  WAVT = (u16*)alloc((size_t)1024*1024*2);
  u16*  WAVEC= (u16*)alloc((size_t)1024*2048*2);
  u16*  WQ   = (u16*)alloc((size_t)512*1024*2);
  u16*  PE   = (u16*)alloc((size_t)256*512*2);
  u16*  WINIT= (u16*)alloc((size_t)1024*1024*2);
  u16*  MEANB= (u16*)alloc((size_t)64*1024*2);
  u16*  XC   = (u16*)alloc((size_t)65*64*2816*2);     // 23.4MB
  u16*  ATT  = (u16*)alloc((size_t)64*64*1024*2);     // 8MB
  float* HWb = (float*)alloc((size_t)64*1024*4);
  float* PM  = (float*)alloc(256*4);
  float* PL  = (float*)alloc(256*4);
  float* CTXP= (float*)alloc((size_t)256*1024*4);
  u16*  Q    = (u16*)alloc((size_t)4096*512*2);
  float* LG  = (float*)alloc((size_t)4096*256*4);
  int*  BAR  = (int*)alloc(512);
  (void)ws_size; (void)in_sizes; (void)n_in; (void)out_size;

  hipMemsetAsync(XC, 0, (size_t)64*2816*2, stream);   // XC[0]
  hipMemsetAsync(BAR, 0, 512, stream);

  k_cast<<<32768,256,0,stream>>>(enc, ENC, (long)64*1024*1024);
  k_cast<<<1024,256,0,stream>>>(W_attvec, WAVEC, (long)1024*2048);
  k_cast<<<256,256,0,stream>>>(W_q2a, WQ, (long)512*1024);
  k_cast<<<64,256,0,stream>>>(prod_emb, PE, (long)256*512);
  k_cast<<<512,256,0,stream>>>(W_init, WINIT, (long)1024*1024);
  k_build_wc<<<5632,256,0,stream>>>(W_ih, W_hh, WC);
  k_wattT<<<4096,256,0,stream>>>(W_att, WAVT);
  k_mean<<<dim3(64,4),256,0,stream>>>(ENC, MEANB);
  k_gemm<2><<<dim3(64,1),256,0,stream>>>(MEANB, 1024L, WINIT, 1024, b_init,
                                         nullptr, 0L, XC + 1792, 2816L);
  k_embed<<<4096,256,0,stream>>>(prod_emb, type_emb, prev_pid, prev_tid, sk_lens, XC);

  k_decoder<<<256,512,0,stream>>>(ENC, WC, WAVT, WAVEC, b_ih, b_hh,
                                  XC, ATT, HWb, PM, PL, CTXP, src_lens, BAR);

  k_gemm<2><<<dim3(32,64),256,0,stream>>>(ATT, 1024L, WQ, 1024, b_q2a,
                                          nullptr, 0L, Q, 512L);
  k_gemm<3><<<dim3(16,64),256,0,stream>>>(Q, 512L, PE, 512, prod_bias,
                                          LG, 256L, nullptr, 0L);
  k_loss<<<64,256,0,stream>>>(LG, target, sk_lens, out);
}

// Round 3
// 5949.224 us; speedup vs baseline: 4.6667x; 4.6667x over previous
//
#include <hip/hip_runtime.h>
#include <hip/hip_bf16.h>

typedef unsigned short u16;
typedef unsigned int u32;
typedef unsigned long long u64;
typedef __attribute__((ext_vector_type(8))) short short8;
typedef __attribute__((ext_vector_type(8))) u16 ushort8;
typedef __attribute__((ext_vector_type(4))) float f32x4;

__device__ __forceinline__ float bf2f(u16 x){ u32 u=((u32)x)<<16; return __builtin_bit_cast(float,u); }
__device__ __forceinline__ u16 f2bf(float f){ u32 u=__builtin_bit_cast(u32,f); u32 r=(u+0x7fffu+((u>>16)&1u))>>16; return (u16)r; }
__device__ __forceinline__ float sigf(float x){ return 1.f/(1.f+__expf(-x)); }

// ---- coherent (L3-direct, sc0sc1) access helpers: RELAXED+AGENT atomics ----
union U16x8 { u64 q[2]; short8 v; };
__device__ __forceinline__ short8 lc16(const u16* p){
  U16x8 u;
  u.q[0] = __hip_atomic_load((const u64*)p,     __ATOMIC_RELAXED, __HIP_MEMORY_SCOPE_AGENT);
  u.q[1] = __hip_atomic_load(((const u64*)p)+1, __ATOMIC_RELAXED, __HIP_MEMORY_SCOPE_AGENT);
  return u.v;
}
__device__ __forceinline__ void lcf2(const float* p, float& a, float& b){
  u64 q = __hip_atomic_load((const u64*)p, __ATOMIC_RELAXED, __HIP_MEMORY_SCOPE_AGENT);
  a = __builtin_bit_cast(float,(u32)q); b = __builtin_bit_cast(float,(u32)(q>>32));
}
__device__ __forceinline__ float lcf(const float* p){
  return __hip_atomic_load(p, __ATOMIC_RELAXED, __HIP_MEMORY_SCOPE_AGENT);
}
__device__ __forceinline__ void scf(float* p, float v){
  __hip_atomic_store(p, v, __ATOMIC_RELAXED, __HIP_MEMORY_SCOPE_AGENT);
}
__device__ __forceinline__ void scf2(float* p, float a, float b){
  u64 q = (u64)__builtin_bit_cast(u32,a) | ((u64)__builtin_bit_cast(u32,b)<<32);
  __hip_atomic_store((u64*)p, q, __ATOMIC_RELAXED, __HIP_MEMORY_SCOPE_AGENT);
}
__device__ __forceinline__ void scu16(u16* p, u16 v){
  __hip_atomic_store(p, v, __ATOMIC_RELAXED, __HIP_MEMORY_SCOPE_AGENT);
}

// ---------------- prologue kernels ----------------

__global__ __launch_bounds__(256) void k_cast(const float* __restrict__ s, u16* __restrict__ d, long n){
  long i = ((long)blockIdx.x*256 + threadIdx.x)*8;
  if (i >= n) return;
  float4 a = *(const float4*)(s+i);
  float4 b = *(const float4*)(s+i+4);
  ushort8 o;
  o[0]=f2bf(a.x); o[1]=f2bf(a.y); o[2]=f2bf(a.z); o[3]=f2bf(a.w);
  o[4]=f2bf(b.x); o[5]=f2bf(b.y); o[6]=f2bf(b.z); o[7]=f2bf(b.w);
  *(ushort8*)(d+i) = o;
}

// Reordered combined weights. x-layout: [a_e(0..511) | t_e(512..767) | att(768..1791) | h(1792..2815)]
// col k: k<512 -> Wih[:,k]; 512..767 -> Wih[:,k+1024]; 768..1791 -> Wih[:,k-256]; >=1792 -> Whh[:,k-1792]
__global__ __launch_bounds__(256) void k_build_wc(const float* __restrict__ Wih, const float* __restrict__ Whh,
                                                  u16* __restrict__ WC){
  long i8 = (long)blockIdx.x*256 + threadIdx.x;           // 4096*352
  if (i8 >= (long)4096*352) return;
  int j = (int)(i8/352); int kk = (int)(i8%352)*8;
  const float* src;
  if (kk < 512)        src = Wih + (long)j*1792 + kk;
  else if (kk < 768)   src = Wih + (long)j*1792 + (kk+1024);
  else if (kk < 1792)  src = Wih + (long)j*1792 + (kk-256);
  else                 src = Whh + (long)j*1024 + (kk-1792);
  u16* dst = WC + (long)j*2816 + kk;
  ushort8 o;
  #pragma unroll
  for (int q=0;q<8;++q) o[q] = f2bf(src[q]);
  *(ushort8*)dst = o;
}

// W_attT[m][k] = W_att[k][m]  (bf16)
__global__ __launch_bounds__(256) void k_wattT(const float* __restrict__ Wa, u16* __restrict__ WT){
  int id = blockIdx.x*256 + threadIdx.x;                  // 1M
  int m = id >> 10, k = id & 1023;
  WT[(long)m*1024 + k] = f2bf(Wa[(long)k*1024 + m]);
}

// mean over S -> bf16 [64][1024]; grid (64,4)
__global__ __launch_bounds__(256) void k_mean(const u16* __restrict__ ENC, u16* __restrict__ MEANB){
  int b = blockIdx.x, h = blockIdx.y*256 + threadIdx.x;
  const u16* p = ENC + ((long)b<<20) + h;
  float s = 0.f;
  for (int ss=0; ss<1024; ++ss) s += bf2f(p[(long)ss<<10]);
  MEANB[b*1024 + h] = f2bf(s * (1.f/1024.f));
}

// a_e / t_e slots (cols 0..767) of XC for all t  (zeros where !prev_valid)
__global__ __launch_bounds__(256) void k_embed(const float* __restrict__ pemb, const float* __restrict__ temb,
      const int* __restrict__ pid, const int* __restrict__ tid_, const int* __restrict__ slen,
      u16* __restrict__ XC){
  int t = blockIdx.x >> 6, b = blockIdx.x & 63;
  bool valid = (t>0) && (t < slen[b]);
  int pi = pid[b*64 + t], ti = tid_[b*64 + t];
  u16* dst = XC + (long)blockIdx.x*2816;
  for (int kk = threadIdx.x; kk < 768; kk += 256){
    float v = 0.f;
    if (valid) v = (kk<512) ? pemb[(long)pi*512 + kk] : temb[(long)ti*256 + (kk-512)];
    dst[kk] = f2bf(v);
  }
}

// generic small GEMM: out = A[M x K] @ W[N x K]^T (block: 64 rows x 16 cols, 4 waves)
// MODE 2: tanh(+bias)->bf16   3: +bias -> f32
template<int MODE>
__global__ __launch_bounds__(256) void k_gemm(const u16* __restrict__ A, long lda,
      const u16* __restrict__ W, int K, const float* __restrict__ bias,
      float* __restrict__ OF, long ldo, u16* __restrict__ OB1, long ldb1){
  int l = threadIdx.x & 63, w = threadIdx.x >> 6;
  int c = l & 15, g = l >> 4;
  int n0 = blockIdx.x*16, m0 = blockIdx.y*64;
  const u16* ap = A + (long)(m0 + w*16 + c)*lda + g*8;
  const u16* bp = W + (long)(n0 + c)*K + g*8;
  f32x4 acc = {0.f,0.f,0.f,0.f};
  int kit = K >> 5;
  #pragma unroll 4
  for (int kb=0; kb<kit; ++kb){
    short8 av = *(const short8*)(ap + kb*32);
    short8 bv = *(const short8*)(bp + kb*32);
    acc = __builtin_amdgcn_mfma_f32_16x16x32_bf16(av, bv, acc, 0, 0, 0);
  }
  #pragma unroll
  for (int r=0;r<4;++r){
    int row = m0 + w*16 + g*4 + r;
    int col = n0 + c;
    float v = acc[r];
    if (MODE==2){ OB1[(long)row*ldb1 + col] = f2bf(tanhf(v + bias[col])); }
    if (MODE==3){ OF[(long)row*ldo + col] = v + bias[col]; }
  }
}

// per-b deterministic loss accumulation
__global__ __launch_bounds__(256) void k_loss(const float* __restrict__ LG, const int* __restrict__ tgt,
      const int* __restrict__ slen, float* __restrict__ out){
  int b = blockIdx.x;
  int w = threadIdx.x >> 6, l = threadIdx.x & 63;
  int len = slen[b];
  float accum = 0.f;
  for (int t = w; t < 64; t += 4){
    if (t >= len) continue;
    const float* lp = LG + ((long)(t*64 + b))*256;
    float v0=lp[l], v1=lp[l+64], v2=lp[l+128], v3=lp[l+192];
    float mx = fmaxf(fmaxf(v0,v1), fmaxf(v2,v3));
    #pragma unroll
    for (int off=32; off; off>>=1) mx = fmaxf(mx, __shfl_xor(mx, off));
    float s = __expf(v0-mx)+__expf(v1-mx)+__expf(v2-mx)+__expf(v3-mx);
    #pragma unroll
    for (int off=32; off; off>>=1) s += __shfl_xor(s, off);
    float ltg = lp[tgt[b*64 + t]];
    float p = __expf(ltg - mx)/s;
    accum += logf(p + 1e-8f);
  }
  __shared__ float sm[4];
  if (l == 0) sm[w] = accum;
  __syncthreads();
  if (threadIdx.x == 0) out[b] = sm[0]+sm[1]+sm[2]+sm[3];
}

// ---------------- persistent decoder ----------------
// Fence-free barrier: inter-phase data uses coherent (sc0sc1) atomics, so the
// barrier needs no wbl2/inv. Monotonic counter, thread-0 relaxed spin.
__device__ __forceinline__ void gsync(int* __restrict__ bar, int nb, int& gen){
  gen += 1;
  __syncthreads();                       // drains vmcnt: sc-stores ack'd at coherence point
  if (threadIdx.x == 0){
    __hip_atomic_fetch_add(bar, 1, __ATOMIC_RELAXED, __HIP_MEMORY_SCOPE_AGENT);
    while (__hip_atomic_load(bar, __ATOMIC_RELAXED, __HIP_MEMORY_SCOPE_AGENT) < gen*nb)
      __builtin_amdgcn_s_sleep(4);
  }
  __syncthreads();
}

__global__ __launch_bounds__(512,2) void k_decoder(
      const u16* __restrict__ ENC, const u16* __restrict__ WC,
      const u16* __restrict__ WAVT, const u16* __restrict__ WAVEC,
      const float* __restrict__ bih, const float* __restrict__ bhh,
      u16* __restrict__ XC, u16* __restrict__ ATT,
      float* __restrict__ HW, float* __restrict__ PM, float* __restrict__ PL,
      float* __restrict__ CTXP, const int* __restrict__ src_lens,
      int* __restrict__ BAR){
  const int tid = threadIdx.x;
  const int w = tid >> 6, l = tid & 63, c = l & 15, g = l >> 4;
  const int bx = blockIdx.x;
  int gen = 0;

  __shared__ float smem[10304];                 // 40.25KB, phase-aliased
  f32x4* lacc  = (f32x4*)smem;                  // P1/P2: [8][64] f32x4 (8KB)
  float* s_ctx = smem;                          // P3: [8][1024] (32KB)
  float* s_mx  = smem + 8192;                   // P3: [8]
  float* s_ls  = smem + 8208;                   // P3: [8]
  u16*   ldsc  = (u16*)smem;                    // P4: [16][1024] bf16 (32KB)
  f32x4* lacc4 = (f32x4*)(smem + 8192);         // P4: [8][64] f32x4 (8KB)

  // P1 constants (block = 4 output-n x 4 gates; waves: mt = w&3 (16 b), kh = w>>2)
  const int n0 = bx << 2;
  const int jrow = n0 + (c & 3) + ((c >> 2) << 10);
  const float biasj = bih[jrow] + bhh[jrow];
  const int kh = w >> 2, mt = w & 3;
  const int lbase = l & 0x33;
  float creg[4] = {0.f,0.f,0.f,0.f};            // c-state lives in registers
  // P2 constants
  const int mt2 = bx & 3, nt2 = bx >> 2;
  // P3 constants
  const int b3 = bx >> 2, p3 = bx & 3;
  int len = src_lens[b3]; if (len < 1) len = 1; if (len > 1024) len = 1024;
  const int chunk = (len + 3) >> 2;
  const int s0 = p3*chunk;
  const int s1 = (s0 + chunk < len) ? (s0 + chunk) : len;
  // P4 constants
  const int mt4 = bx & 3, nt4 = bx >> 2;
  const int b16 = tid >> 5, lane32 = tid & 31;

  for (int t = 0; t < 64; ++t){
    const u16* XCt = XC + (size_t)t*64*2816;
    u16* XCn = XC + (size_t)(t+1)*64*2816;
    const u16* Hcur = XCn + 1792;               // h_t, row stride 2816

    // ---- P1: gates GEMM (split-K x2) + LSTM pointwise; h -> XCn (coherent) ----
    {
      const u16* ap = XCt + (long)(mt*16 + c)*2816 + kh*1408 + g*8;
      const u16* bp = WC  + (long)jrow*2816 + kh*1408 + g*8;
      f32x4 acc = {0.f,0.f,0.f,0.f};
      if (kh == 0){
        #pragma unroll 8
        for (int kb=0; kb<24; ++kb){            // cols 0..767: embeds, cacheable
          short8 av = *(const short8*)(ap + kb*32);
          short8 bv = *(const short8*)(bp + kb*32);
          acc = __builtin_amdgcn_mfma_f32_16x16x32_bf16(av, bv, acc, 0, 0, 0);
        }
        #pragma unroll 4
        for (int kb=24; kb<44; ++kb){           // cols 768..1407: att, coherent
          short8 av = lc16(ap + kb*32);
          short8 bv = *(const short8*)(bp + kb*32);
          acc = __builtin_amdgcn_mfma_f32_16x16x32_bf16(av, bv, acc, 0, 0, 0);
        }
      } else {
        #pragma unroll 4
        for (int kb=0; kb<44; ++kb){            // cols 1408..2815: att|h, coherent
          short8 av = lc16(ap + kb*32);
          short8 bv = *(const short8*)(bp + kb*32);
          acc = __builtin_amdgcn_mfma_f32_16x16x32_bf16(av, bv, acc, 0, 0, 0);
        }
      }
      lacc[w*64 + l] = acc;
      __syncthreads();
      if (w < 4){
        f32x4 a0 = lacc[w*64 + l];
        f32x4 a1 = lacc[(w+4)*64 + l];
        #pragma unroll
        for (int r=0;r<4;++r){
          float val = a0[r] + a1[r] + biasj;
          float iv = __shfl(val, lbase);
          float fv = __shfl(val, lbase+4);
          float gv = __shfl(val, lbase+8);
          float ov = __shfl(val, lbase+12);
          if ((l & 12) == 0){
            float cn = sigf(fv)*creg[r] + sigf(iv)*tanhf(gv);
            float hn = sigf(ov)*tanhf(cn);
            creg[r] = cn;
            int b = w*16 + g*4 + r;
            int n = n0 + (l & 3);
            scu16(XCn + (long)b*2816 + 1792 + n, f2bf(hn));
          }
        }
      }
    }
    gsync(BAR, 256, gen);

    // ---- P2: HW = h @ W_att^T  (8-way split-K, LDS reduce) ----
    {
      const u16* ap = Hcur + (long)(mt2*16 + c)*2816 + w*128 + g*8;
      const u16* bp = WAVT + (long)(nt2*16 + c)*1024 + w*128 + g*8;
      f32x4 acc = {0.f,0.f,0.f,0.f};
      #pragma unroll
      for (int kb=0; kb<4; ++kb){
        short8 av = lc16(ap + kb*32);
        short8 bv = *(const short8*)(bp + kb*32);
        acc = __builtin_amdgcn_mfma_f32_16x16x32_bf16(av, bv, acc, 0, 0, 0);
      }
      lacc[w*64 + l] = acc;
      __syncthreads();
      if (w == 0){
        f32x4 rd = lacc[l];
        #pragma unroll
        for (int w2=1; w2<8; ++w2) rd += lacc[w2*64 + l];
        #pragma unroll
        for (int r=0;r<4;++r)
          scf(HW + (long)(mt2*16 + g*4 + r)*1024 + nt2*16 + c, rd[r]);
      }
    }
    gsync(BAR, 256, gen);

    // ---- P3: attention partials (online softmax over s-chunk, 8 waves) ----
    {
      float hw[16], ctx[16];
      const float* hwp = HW + b3*1024 + l*16;
      #pragma unroll
      for (int jj=0;jj<8;++jj) lcf2(hwp + jj*2, hw[2*jj], hw[2*jj+1]);
      #pragma unroll
      for (int jj=0;jj<16;++jj) ctx[jj]=0.f;
      float m = -INFINITY, lsum = 0.f;
      for (int s = s0 + w; s < s1; s += 8){
        const u16* ep = ENC + (((long)(b3*1024 + s))<<10) + l*16;
        uint4 q0 = *(const uint4*)ep;
        uint4 q1 = *(const uint4*)(ep + 8);
        float e[16];
        e[0]=bf2f((u16)(q0.x&0xffff)); e[1]=bf2f((u16)(q0.x>>16));
        e[2]=bf2f((u16)(q0.y&0xffff)); e[3]=bf2f((u16)(q0.y>>16));
        e[4]=bf2f((u16)(q0.z&0xffff)); e[5]=bf2f((u16)(q0.z>>16));
        e[6]=bf2f((u16)(q0.w&0xffff)); e[7]=bf2f((u16)(q0.w>>16));
        e[8]=bf2f((u16)(q1.x&0xffff)); e[9]=bf2f((u16)(q1.x>>16));
        e[10]=bf2f((u16)(q1.y&0xffff)); e[11]=bf2f((u16)(q1.y>>16));
        e[12]=bf2f((u16)(q1.z&0xffff)); e[13]=bf2f((u16)(q1.z>>16));
        e[14]=bf2f((u16)(q1.w&0xffff)); e[15]=bf2f((u16)(q1.w>>16));
        float sc = 0.f;
        #pragma unroll
        for (int jj=0;jj<16;++jj) sc += e[jj]*hw[jj];
        #pragma unroll
        for (int off=32; off; off>>=1) sc += __shfl_xor(sc, off);
        float nm = fmaxf(m, sc);
        float pe = __expf(sc - nm);
        if (nm > m){
          float corr = __expf(m - nm);
          lsum *= corr;
          #pragma unroll
          for (int jj=0;jj<16;++jj) ctx[jj] *= corr;
          m = nm;
        }
        lsum += pe;
        #pragma unroll
        for (int jj=0;jj<16;++jj) ctx[jj] += pe*e[jj];
      }
      #pragma unroll
      for (int jj=0;jj<16;++jj) s_ctx[w*1024 + l*16 + jj] = ctx[jj];
      if (l == 0){ s_mx[w] = m; s_ls[w] = lsum; }
      __syncthreads();
      float M8 = s_mx[0];
      #pragma unroll
      for (int q=1;q<8;++q) M8 = fmaxf(M8, s_mx[q]);
      float wei[8]; float L = 0.f;
      #pragma unroll
      for (int q=0;q<8;++q){
        wei[q] = (s_mx[q] == -INFINITY) ? 0.f : __expf(s_mx[q]-M8);
        L += wei[q]*s_ls[q];
      }
      {
        int mm = tid*2;
        float v0 = 0.f, v1 = 0.f;
        #pragma unroll
        for (int p=0;p<8;++p){ v0 += wei[p]*s_ctx[p*1024 + mm]; v1 += wei[p]*s_ctx[p*1024 + mm + 1]; }
        scf2(CTXP + (long)bx*1024 + mm, v0, v1);
      }
      if (tid == 0){ scf(PM + bx, M8); scf(PL + bx, L); }
    }
    gsync(BAR, 256, gen);

    // ---- P4: ctx combine (16 b -> LDS, swizzled) + att = tanh([h|ctx]@W_attvec^T) ----
    {
      int b = mt4*16 + b16;
      float m0=lcf(PM+b*4), m1=lcf(PM+b*4+1), m2=lcf(PM+b*4+2), m3=lcf(PM+b*4+3);
      float M = fmaxf(fmaxf(m0,m1), fmaxf(m2,m3));
      float w0 = (m0==-INFINITY)?0.f:__expf(m0-M);
      float w1 = (m1==-INFINITY)?0.f:__expf(m1-M);
      float w2 = (m2==-INFINITY)?0.f:__expf(m2-M);
      float w3 = (m3==-INFINITY)?0.f:__expf(m3-M);
      float L = w0*lcf(PL+b*4) + w1*lcf(PL+b*4+1) + w2*lcf(PL+b*4+2) + w3*lcf(PL+b*4+3);
      float inv = (L > 0.f) ? 1.f/L : 0.f;
      const float* c0 = CTXP + (long)(b*4+0)*1024;
      const float* c1 = CTXP + (long)(b*4+1)*1024;
      const float* c2 = CTXP + (long)(b*4+2)*1024;
      const float* c3 = CTXP + (long)(b*4+3)*1024;
      const int swz = (b16 & 7) << 3;
      #pragma unroll 4
      for (int q=0;q<16;++q){
        int mcol = (lane32 + q*32)*2;
        float a0,b0,a1,b1,a2,b2,a3,b3;
        lcf2(c0+mcol,a0,b0); lcf2(c1+mcol,a1,b1); lcf2(c2+mcol,a2,b2); lcf2(c3+mcol,a3,b3);
        float v0 = (w0*a0 + w1*a1 + w2*a2 + w3*a3) * inv;
        float v1 = (w0*b0 + w1*b1 + w2*b2 + w3*b3) * inv;
        ldsc[(b16*1024 + mcol) ^ swz]     = f2bf(v0);
        ldsc[(b16*1024 + mcol + 1) ^ swz] = f2bf(v1);
      }
      __syncthreads();
      f32x4 acc = {0.f,0.f,0.f,0.f};
      const u16* bp = WAVEC + (long)(nt4*16 + c)*2048 + w*256 + g*8;
      if (w < 4){
        const u16* ap = Hcur + (long)(mt4*16 + c)*2816 + w*256 + g*8;
        #pragma unroll 4
        for (int kb=0; kb<8; ++kb){
          short8 av = lc16(ap + kb*32);
          short8 bv = *(const short8*)(bp + kb*32);
          acc = __builtin_amdgcn_mfma_f32_16x16x32_bf16(av, bv, acc, 0, 0, 0);
        }
      } else {
        const int cswz = (c & 7) << 3;
        const int kbase = c*1024 + (w-4)*256 + g*8;
        #pragma unroll
        for (int kb=0; kb<8; ++kb){
          short8 av = *(const short8*)(ldsc + ((kbase + kb*32) ^ cswz));
          short8 bv = *(const short8*)(bp + kb*32);
          acc = __builtin_amdgcn_mfma_f32_16x16x32_bf16(av, bv, acc, 0, 0, 0);
        }
      }
      lacc4[w*64 + l] = acc;
      __syncthreads();
      if (w == 0){
        f32x4 rd = lacc4[l];
        #pragma unroll
        for (int w2=1; w2<8; ++w2) rd += lacc4[w2*64 + l];
        #pragma unroll
        for (int r=0;r<4;++r){
          int b_ = mt4*16 + g*4 + r;
          int col = nt4*16 + c;
          u16 x = f2bf(tanhf(rd[r]));
          scu16(XCn + (long)b_*2816 + 768 + col, x);
          ATT[((long)t*64 + b_)*1024 + col] = x;
        }
      }
    }
    gsync(BAR, 256, gen);
  }
}

extern "C" void kernel_launch(void* const* d_in, const int* in_sizes, int n_in,
                              void* d_out, int out_size, void* d_ws, size_t ws_size,
                              hipStream_t stream){
  const float* enc      = (const float*)d_in[0];
  const float* W_ih     = (const float*)d_in[1];
  const float* b_ih     = (const float*)d_in[2];
  const float* W_hh     = (const float*)d_in[3];
  const float* b_hh     = (const float*)d_in[4];
  const float* W_att    = (const float*)d_in[5];
  const float* W_attvec = (const float*)d_in[6];
  const float* W_init   = (const float*)d_in[7];
  const float* b_init   = (const float*)d_in[8];
  const float* W_q2a    = (const float*)d_in[9];
  const float* b_q2a    = (const float*)d_in[10];
  const float* prod_emb = (const float*)d_in[11];
  const float* prod_bias= (const float*)d_in[12];
  const float* type_emb = (const float*)d_in[13];
  const int* prev_pid   = (const int*)d_in[14];
  const int* prev_tid   = (const int*)d_in[15];
  const int* target     = (const int*)d_in[16];
  const int* sk_lens    = (const int*)d_in[17];
  const int* src_lens   = (const int*)d_in[18];
  float* out = (float*)d_out;

  char* ws = (char*)d_ws;
  size_t o = 0;
  auto alloc = [&](size_t bytes)->char*{ char* p = ws + o; o += (bytes + 255) & ~(size_t)255; return p; };
  u16*  ENC  = (u16*)alloc((size_t)64*1024*1024*2);   // 128MB
  u16*  WC   = (u16*)alloc((size_t)4096*2816*2);      // 22.5MB
  u16*  WAVT = (u16*)alloc((size_t)1024*1024*2);
  u16*  WAVEC= (u16*)alloc((size_t)1024*2048*2);
  u16*  WQ   = (u16*)alloc((size_t)512*1024*2);
  u16*  PE   = (u16*)alloc((size_t)256*512*2);
  u16*  WINIT= (u16*)alloc((size_t)1024*1024*2);
  u16*  MEANB= (u16*)alloc((size_t)64*1024*2);
  u16*  XC   = (u16*)alloc((size_t)65*64*2816*2);     // 23.4MB
  u16*  ATT  = (u16*)alloc((size_t)64*64*1024*2);     // 8MB
  float* HWb = (float*)alloc((size_t)64*1024*4);
  float* PM  = (float*)alloc(256*4);
  float* PL  = (float*)alloc(256*4);
  float* CTXP= (float*)alloc((size_t)256*1024*4);
  u16*  Q    = (u16*)alloc((size_t)4096*512*2);
  float* LG  = (float*)alloc((size_t)4096*256*4);
  int*  BAR  = (int*)alloc(512);
  (void)ws_size; (void)in_sizes; (void)n_in; (void)out_size;

  hipMemsetAsync(XC, 0, (size_t)64*2816*2, stream);   // XC[0]: embeds+att zero; h by init GEMM
  hipMemsetAsync(BAR, 0, 512, stream);

  k_cast<<<32768,256,0,stream>>>(enc, ENC, (long)64*1024*1024);
  k_cast<<<1024,256,0,stream>>>(W_attvec, WAVEC, (long)1024*2048);
  k_cast<<<256,256,0,stream>>>(W_q2a, WQ, (long)512*1024);
  k_cast<<<64,256,0,stream>>>(prod_emb, PE, (long)256*512);
  k_cast<<<512,256,0,stream>>>(W_init, WINIT, (long)1024*1024);
  k_build_wc<<<5632,256,0,stream>>>(W_ih, W_hh, WC);
  k_wattT<<<4096,256,0,stream>>>(W_att, WAVT);
  k_mean<<<dim3(64,4),256,0,stream>>>(ENC, MEANB);
  k_gemm<2><<<dim3(64,1),256,0,stream>>>(MEANB, 1024L, WINIT, 1024, b_init,
                                         nullptr, 0L, XC + 1792, 2816L);
  k_embed<<<4096,256,0,stream>>>(prod_emb, type_emb, prev_pid, prev_tid, sk_lens, XC);

  k_decoder<<<256,512,0,stream>>>(ENC, WC, WAVT, WAVEC, b_ih, b_hh,
                                  XC, ATT, HWb, PM, PL, CTXP, src_lens, BAR);

  k_gemm<2><<<dim3(32,64),256,0,stream>>>(ATT, 1024L, WQ, 1024, b_q2a,
                                          nullptr, 0L, Q, 512L);
  k_gemm<3><<<dim3(16,64),256,0,stream>>>(Q, 512L, PE, 512, prod_bias,
                                          LG, 256L, nullptr, 0L);
  k_loss<<<64,256,0,stream>>>(LG, target, sk_lens, out);
}

// Round 4
// 4863.929 us; speedup vs baseline: 5.7080x; 1.2231x over previous
//
#include <hip/hip_runtime.h>
#include <hip/hip_bf16.h>

typedef unsigned short u16;
typedef unsigned int u32;
typedef unsigned long long u64;
typedef __attribute__((ext_vector_type(8))) short short8;
typedef __attribute__((ext_vector_type(8))) u16 ushort8;
typedef __attribute__((ext_vector_type(4))) u16 ushort4v;
typedef __attribute__((ext_vector_type(4))) float f32x4;

__device__ __forceinline__ float bf2f(u16 x){ u32 u=((u32)x)<<16; return __builtin_bit_cast(float,u); }
__device__ __forceinline__ u16 f2bf(float f){ u32 u=__builtin_bit_cast(u32,f); u32 r=(u+0x7fffu+((u>>16)&1u))>>16; return (u16)r; }
__device__ __forceinline__ float sigf(float x){ return 1.f/(1.f+__expf(-x)); }

// coherent STORES only (write-through to memory-side L3). Loads are all plain;
// correctness from first-touch-after-write (time-indexed buffers).
__device__ __forceinline__ void scf(float* p, float v){
  __hip_atomic_store(p, v, __ATOMIC_RELAXED, __HIP_MEMORY_SCOPE_AGENT);
}
__device__ __forceinline__ void scf2(float* p, float a, float b){
  u64 q = (u64)__builtin_bit_cast(u32,a) | ((u64)__builtin_bit_cast(u32,b)<<32);
  __hip_atomic_store((u64*)p, q, __ATOMIC_RELAXED, __HIP_MEMORY_SCOPE_AGENT);
}
__device__ __forceinline__ void scu16(u16* p, u16 v){
  __hip_atomic_store(p, v, __ATOMIC_RELAXED, __HIP_MEMORY_SCOPE_AGENT);
}

// ---------------- prologue kernels ----------------

__global__ __launch_bounds__(256) void k_cast(const float* __restrict__ s, u16* __restrict__ d, long n){
  long i = ((long)blockIdx.x*256 + threadIdx.x)*8;
  if (i >= n) return;
  float4 a = *(const float4*)(s+i);
  float4 b = *(const float4*)(s+i+4);
  ushort8 o;
  o[0]=f2bf(a.x); o[1]=f2bf(a.y); o[2]=f2bf(a.z); o[3]=f2bf(a.w);
  o[4]=f2bf(b.x); o[5]=f2bf(b.y); o[6]=f2bf(b.z); o[7]=f2bf(b.w);
  *(ushort8*)(d+i) = o;
}

// Reordered combined weights. x-layout: [a_e(0..511) | t_e(512..767) | att(768..1791) | h(1792..2815)]
__global__ __launch_bounds__(256) void k_build_wc(const float* __restrict__ Wih, const float* __restrict__ Whh,
                                                  u16* __restrict__ WC){
  long i8 = (long)blockIdx.x*256 + threadIdx.x;           // 4096*352
  if (i8 >= (long)4096*352) return;
  int j = (int)(i8/352); int kk = (int)(i8%352)*8;
  const float* src;
  if (kk < 512)        src = Wih + (long)j*1792 + kk;
  else if (kk < 768)   src = Wih + (long)j*1792 + (kk+1024);
  else if (kk < 1792)  src = Wih + (long)j*1792 + (kk-256);
  else                 src = Whh + (long)j*1024 + (kk-1792);
  u16* dst = WC + (long)j*2816 + kk;
  ushort8 o;
  #pragma unroll
  for (int q=0;q<8;++q) o[q] = f2bf(src[q]);
  *(ushort8*)dst = o;
}

__global__ __launch_bounds__(256) void k_wattT(const float* __restrict__ Wa, u16* __restrict__ WT){
  int id = blockIdx.x*256 + threadIdx.x;                  // 1M
  int m = id >> 10, k = id & 1023;
  WT[(long)m*1024 + k] = f2bf(Wa[(long)k*1024 + m]);
}

__global__ __launch_bounds__(256) void k_mean(const u16* __restrict__ ENC, u16* __restrict__ MEANB){
  int b = blockIdx.x, h = blockIdx.y*256 + threadIdx.x;
  const u16* p = ENC + ((long)b<<20) + h;
  float s = 0.f;
  for (int ss=0; ss<1024; ++ss) s += bf2f(p[(long)ss<<10]);
  MEANB[b*1024 + h] = f2bf(s * (1.f/1024.f));
}

__global__ __launch_bounds__(256) void k_embed(const float* __restrict__ pemb, const float* __restrict__ temb,
      const int* __restrict__ pid, const int* __restrict__ tid_, const int* __restrict__ slen,
      u16* __restrict__ XC){
  int t = blockIdx.x >> 6, b = blockIdx.x & 63;
  bool valid = (t>0) && (t < slen[b]);
  int pi = pid[b*64 + t], ti = tid_[b*64 + t];
  u16* dst = XC + (long)blockIdx.x*2816;
  for (int kk = threadIdx.x; kk < 768; kk += 256){
    float v = 0.f;
    if (valid) v = (kk<512) ? pemb[(long)pi*512 + kk] : temb[(long)ti*256 + (kk-512)];
    dst[kk] = f2bf(v);
  }
}

// generic small GEMM: out = A[M x K] @ W[N x K]^T (block: 64 rows x 16 cols, 4 waves)
template<int MODE>
__global__ __launch_bounds__(256) void k_gemm(const u16* __restrict__ A, long lda,
      const u16* __restrict__ W, int K, const float* __restrict__ bias,
      float* __restrict__ OF, long ldo, u16* __restrict__ OB1, long ldb1){
  int l = threadIdx.x & 63, w = threadIdx.x >> 6;
  int c = l & 15, g = l >> 4;
  int n0 = blockIdx.x*16, m0 = blockIdx.y*64;
  const u16* ap = A + (long)(m0 + w*16 + c)*lda + g*8;
  const u16* bp = W + (long)(n0 + c)*K + g*8;
  f32x4 acc = {0.f,0.f,0.f,0.f};
  int kit = K >> 5;
  #pragma unroll 4
  for (int kb=0; kb<kit; ++kb){
    short8 av = *(const short8*)(ap + kb*32);
    short8 bv = *(const short8*)(bp + kb*32);
    acc = __builtin_amdgcn_mfma_f32_16x16x32_bf16(av, bv, acc, 0, 0, 0);
  }
  #pragma unroll
  for (int r=0;r<4;++r){
    int row = m0 + w*16 + g*4 + r;
    int col = n0 + c;
    float v = acc[r];
    if (MODE==2){ OB1[(long)row*ldb1 + col] = f2bf(tanhf(v + bias[col])); }
    if (MODE==3){ OF[(long)row*ldo + col] = v + bias[col]; }
  }
}

__global__ __launch_bounds__(256) void k_loss(const float* __restrict__ LG, const int* __restrict__ tgt,
      const int* __restrict__ slen, float* __restrict__ out){
  int b = blockIdx.x;
  int w = threadIdx.x >> 6, l = threadIdx.x & 63;
  int len = slen[b];
  float accum = 0.f;
  for (int t = w; t < 64; t += 4){
    if (t >= len) continue;
    const float* lp = LG + ((long)(t*64 + b))*256;
    float v0=lp[l], v1=lp[l+64], v2=lp[l+128], v3=lp[l+192];
    float mx = fmaxf(fmaxf(v0,v1), fmaxf(v2,v3));
    #pragma unroll
    for (int off=32; off; off>>=1) mx = fmaxf(mx, __shfl_xor(mx, off));
    float s = __expf(v0-mx)+__expf(v1-mx)+__expf(v2-mx)+__expf(v3-mx);
    #pragma unroll
    for (int off=32; off; off>>=1) s += __shfl_xor(s, off);
    float ltg = lp[tgt[b*64 + t]];
    float p = __expf(ltg - mx)/s;
    accum += logf(p + 1e-8f);
  }
  __shared__ float sm[4];
  if (l == 0) sm[w] = accum;
  __syncthreads();
  if (threadIdx.x == 0) out[b] = sm[0]+sm[1]+sm[2]+sm[3];
}

// ---------------- persistent decoder ----------------
// Fence-free barrier: producers' sc0sc1 stores are drained by __syncthreads'
// vmcnt(0) before thread0's arrival add; consumers only plain-load regions
// that are first-touch-after-write (time-indexed buffers).
__device__ __forceinline__ void gsync(int* __restrict__ bar, int nb, int& gen){
  gen += 1;
  __syncthreads();
  if (threadIdx.x == 0){
    __hip_atomic_fetch_add(bar, 1, __ATOMIC_RELAXED, __HIP_MEMORY_SCOPE_AGENT);
    while (__hip_atomic_load(bar, __ATOMIC_RELAXED, __HIP_MEMORY_SCOPE_AGENT) < gen*nb)
      __builtin_amdgcn_s_sleep(2);
  }
  __syncthreads();
}

__global__ __launch_bounds__(512,1) void k_decoder(
      const u16* __restrict__ ENC, const u16* __restrict__ WC,
      const u16* __restrict__ WAVT, const u16* __restrict__ WAVEC,
      const float* __restrict__ bih, const float* __restrict__ bhh,
      u16* __restrict__ XC, u16* __restrict__ ATT,
      float* __restrict__ HWT, float* __restrict__ PMT, float* __restrict__ PLT,
      float* __restrict__ CTXPT, const int* __restrict__ src_lens,
      int* __restrict__ BAR){
  const int tid = threadIdx.x;
  const int w = tid >> 6, l = tid & 63, c = l & 15, g = l >> 4;
  const int bx = blockIdx.x;
  int gen = 0;

  __shared__ float smem[10304];                 // 40.25KB, phase-aliased
  f32x4* lacc  = (f32x4*)smem;                  // P1/P2: [8][64] f32x4 (8KB)
  float* s_ctx = smem;                          // P3: [8][1024] (32KB)
  float* s_mx  = smem + 8192;
  float* s_ls  = smem + 8208;
  u16*   ldsc  = (u16*)smem;                    // P4: [16][1024] bf16 (32KB)
  f32x4* lacc4 = (f32x4*)(smem + 8192);         // P4: [8][64] f32x4 (8KB)

  // P1 constants
  const int n0 = bx << 2;
  const int jrow = n0 + (c & 3) + ((c >> 2) << 10);
  const float biasj = bih[jrow] + bhh[jrow];
  const int kh = w >> 2, mt = w & 3;
  const int lbase = l & 0x33;
  float creg[4] = {0.f,0.f,0.f,0.f};
  // P2 constants
  const int mt2 = bx & 3, nt2 = bx >> 2;
  // P3 constants
  const int b3 = bx >> 2, p3 = bx & 3;
  int len = src_lens[b3]; if (len < 1) len = 1; if (len > 1024) len = 1024;
  const int chunk = (len + 3) >> 2;
  const int s0 = p3*chunk;
  const int s1 = (s0 + chunk < len) ? (s0 + chunk) : len;
  // P4 constants
  const int mt4 = bx & 3, nt4 = bx >> 2;
  const int b16 = tid >> 5, lane32 = tid & 31;

  for (int t = 0; t < 64; ++t){
    const u16* XCt = XC + (size_t)t*64*2816;
    u16* XCn = XC + (size_t)(t+1)*64*2816;
    const u16* Hcur = XCn + 1792;
    float* HW   = HWT  + (size_t)t*64*1024;
    float* PM   = PMT  + (size_t)t*256;
    float* PL   = PLT  + (size_t)t*256;
    float* CTXP = CTXPT + (size_t)t*256*1024;

    // ---- P1: gates GEMM (split-K x2, plain loads) + LSTM pointwise ----
    {
      const u16* ap = XCt + (long)(mt*16 + c)*2816 + kh*1408 + g*8;
      const u16* bp = WC  + (long)jrow*2816 + kh*1408 + g*8;
      f32x4 acc = {0.f,0.f,0.f,0.f};
      #pragma unroll 4
      for (int kb=0; kb<44; ++kb){
        short8 av = *(const short8*)(ap + kb*32);
        short8 bv = *(const short8*)(bp + kb*32);
        acc = __builtin_amdgcn_mfma_f32_16x16x32_bf16(av, bv, acc, 0, 0, 0);
      }
      lacc[w*64 + l] = acc;
      __syncthreads();
      if (w < 4){
        f32x4 a0 = lacc[w*64 + l];
        f32x4 a1 = lacc[(w+4)*64 + l];
        #pragma unroll
        for (int r=0;r<4;++r){
          float val = a0[r] + a1[r] + biasj;
          float iv = __shfl(val, lbase);
          float fv = __shfl(val, lbase+4);
          float gv = __shfl(val, lbase+8);
          float ov = __shfl(val, lbase+12);
          if ((l & 12) == 0){
            float cn = sigf(fv)*creg[r] + sigf(iv)*tanhf(gv);
            float hn = sigf(ov)*tanhf(cn);
            creg[r] = cn;
            int b = w*16 + g*4 + r;
            int n = n0 + (l & 3);
            scu16(XCn + (long)b*2816 + 1792 + n, f2bf(hn));
          }
        }
      }
    }
    gsync(BAR, 256, gen);

    // ---- P2: HW = h @ W_att^T (8-way split-K, plain loads) ----
    {
      const u16* ap = Hcur + (long)(mt2*16 + c)*2816 + w*128 + g*8;
      const u16* bp = WAVT + (long)(nt2*16 + c)*1024 + w*128 + g*8;
      f32x4 acc = {0.f,0.f,0.f,0.f};
      #pragma unroll
      for (int kb=0; kb<4; ++kb){
        short8 av = *(const short8*)(ap + kb*32);
        short8 bv = *(const short8*)(bp + kb*32);
        acc = __builtin_amdgcn_mfma_f32_16x16x32_bf16(av, bv, acc, 0, 0, 0);
      }
      lacc[w*64 + l] = acc;
      __syncthreads();
      if (w == 0){
        f32x4 rd = lacc[l];
        #pragma unroll
        for (int w2=1; w2<8; ++w2) rd += lacc[w2*64 + l];
        #pragma unroll
        for (int r=0;r<4;++r)
          scf(HW + (long)(mt2*16 + g*4 + r)*1024 + nt2*16 + c, rd[r]);
      }
    }
    gsync(BAR, 256, gen);

    // ---- P3: attention partials, pair-unrolled online softmax ----
    {
      float hw[16], ctx[16];
      const float* hwp = HW + b3*1024 + l*16;
      #pragma unroll
      for (int jj=0;jj<4;++jj){
        float4 v = *(const float4*)(hwp + jj*4);
        hw[4*jj]=v.x; hw[4*jj+1]=v.y; hw[4*jj+2]=v.z; hw[4*jj+3]=v.w;
      }
      #pragma unroll
      for (int jj=0;jj<16;++jj) ctx[jj]=0.f;
      float m = -INFINITY, lsum = 0.f;
      for (int s = s0 + w; s < s1; s += 16){
        bool hasB = (s + 8 < s1);
        int sB = hasB ? (s + 8) : s;
        const u16* epA = ENC + (((long)(b3*1024 + s ))<<10) + l*16;
        const u16* epB = ENC + (((long)(b3*1024 + sB))<<10) + l*16;
        uint4 qa0 = *(const uint4*)epA;
        uint4 qa1 = *(const uint4*)(epA + 8);
        uint4 qb0 = *(const uint4*)epB;
        uint4 qb1 = *(const uint4*)(epB + 8);
        float eA[16], eB[16];
        #pragma unroll
        for (int jj=0;jj<4;++jj){
          u32 xa0=((const u32*)&qa0)[jj], xa1=((const u32*)&qa1)[jj];
          u32 xb0=((const u32*)&qb0)[jj], xb1=((const u32*)&qb1)[jj];
          eA[2*jj]   = bf2f((u16)(xa0&0xffff)); eA[2*jj+1] = bf2f((u16)(xa0>>16));
          eA[8+2*jj] = bf2f((u16)(xa1&0xffff)); eA[8+2*jj+1] = bf2f((u16)(xa1>>16));
          eB[2*jj]   = bf2f((u16)(xb0&0xffff)); eB[2*jj+1] = bf2f((u16)(xb0>>16));
          eB[8+2*jj] = bf2f((u16)(xb1&0xffff)); eB[8+2*jj+1] = bf2f((u16)(xb1>>16));
        }
        float scA = 0.f, scB = 0.f;
        #pragma unroll
        for (int jj=0;jj<16;++jj){ scA += eA[jj]*hw[jj]; scB += eB[jj]*hw[jj]; }
        #pragma unroll
        for (int off=32; off; off>>=1){
          scA += __shfl_xor(scA, off);
          scB += __shfl_xor(scB, off);
        }
        if (!hasB) scB = -INFINITY;
        float nm = fmaxf(m, fmaxf(scA, scB));
        float corr = __expf(m - nm);          // m=-inf first iter -> 0
        float peA = __expf(scA - nm);
        float peB = __expf(scB - nm);         // scB=-inf -> 0
        lsum = lsum*corr + peA + peB;
        #pragma unroll
        for (int jj=0;jj<16;++jj) ctx[jj] = ctx[jj]*corr + peA*eA[jj] + peB*eB[jj];
        m = nm;
      }
      #pragma unroll
      for (int jj=0;jj<16;++jj) s_ctx[w*1024 + l*16 + jj] = ctx[jj];
      if (l == 0){ s_mx[w] = m; s_ls[w] = lsum; }
      __syncthreads();
      float M8 = s_mx[0];
      #pragma unroll
      for (int q=1;q<8;++q) M8 = fmaxf(M8, s_mx[q]);
      float wei[8]; float L = 0.f;
      #pragma unroll
      for (int q=0;q<8;++q){
        wei[q] = (s_mx[q] == -INFINITY) ? 0.f : __expf(s_mx[q]-M8);
        L += wei[q]*s_ls[q];
      }
      {
        int mm = tid*2;
        float v0 = 0.f, v1 = 0.f;
        #pragma unroll
        for (int p=0;p<8;++p){ v0 += wei[p]*s_ctx[p*1024 + mm]; v1 += wei[p]*s_ctx[p*1024 + mm + 1]; }
        scf2(CTXP + (long)bx*1024 + mm, v0, v1);
      }
      if (tid == 0){ scf(PM + bx, M8); scf(PL + bx, L); }
    }
    gsync(BAR, 256, gen);

    // ---- P4: ctx combine (plain float4 loads -> LDS swz) + att GEMM ----
    {
      int b = mt4*16 + b16;
      const float* pmb = PM + b*4;
      const float* plb = PL + b*4;
      float m0=pmb[0], m1=pmb[1], m2=pmb[2], m3=pmb[3];
      float M = fmaxf(fmaxf(m0,m1), fmaxf(m2,m3));
      float w0 = (m0==-INFINITY)?0.f:__expf(m0-M);
      float w1 = (m1==-INFINITY)?0.f:__expf(m1-M);
      float w2 = (m2==-INFINITY)?0.f:__expf(m2-M);
      float w3 = (m3==-INFINITY)?0.f:__expf(m3-M);
      float L = w0*plb[0] + w1*plb[1] + w2*plb[2] + w3*plb[3];
      float inv = (L > 0.f) ? 1.f/L : 0.f;
      const float* c0 = CTXP + (long)(b*4+0)*1024;
      const float* c1 = CTXP + (long)(b*4+1)*1024;
      const float* c2 = CTXP + (long)(b*4+2)*1024;
      const float* c3 = CTXP + (long)(b*4+3)*1024;
      const int swz = (b16 & 7) << 3;
      #pragma unroll
      for (int q=0;q<8;++q){
        int mcol = (lane32 + q*32)*4;
        float4 a0 = *(const float4*)(c0 + mcol);
        float4 a1 = *(const float4*)(c1 + mcol);
        float4 a2 = *(const float4*)(c2 + mcol);
        float4 a3 = *(const float4*)(c3 + mcol);
        ushort4v o;
        o[0] = f2bf((w0*a0.x + w1*a1.x + w2*a2.x + w3*a3.x) * inv);
        o[1] = f2bf((w0*a0.y + w1*a1.y + w2*a2.y + w3*a3.y) * inv);
        o[2] = f2bf((w0*a0.z + w1*a1.z + w2*a2.z + w3*a3.z) * inv);
        o[3] = f2bf((w0*a0.w + w1*a1.w + w2*a2.w + w3*a3.w) * inv);
        *(ushort4v*)(ldsc + ((b16*1024 + mcol) ^ swz)) = o;
      }
      __syncthreads();
      f32x4 acc = {0.f,0.f,0.f,0.f};
      const u16* bp = WAVEC + (long)(nt4*16 + c)*2048 + w*256 + g*8;
      if (w < 4){
        const u16* ap = Hcur + (long)(mt4*16 + c)*2816 + w*256 + g*8;
        #pragma unroll
        for (int kb=0; kb<8; ++kb){
          short8 av = *(const short8*)(ap + kb*32);
          short8 bv = *(const short8*)(bp + kb*32);
          acc = __builtin_amdgcn_mfma_f32_16x16x32_bf16(av, bv, acc, 0, 0, 0);
        }
      } else {
        const int cswz = (c & 7) << 3;
        const int kbase = c*1024 + (w-4)*256 + g*8;
        #pragma unroll
        for (int kb=0; kb<8; ++kb){
          short8 av = *(const short8*)(ldsc + ((kbase + kb*32) ^ cswz));
          short8 bv = *(const short8*)(bp + kb*32);
          acc = __builtin_amdgcn_mfma_f32_16x16x32_bf16(av, bv, acc, 0, 0, 0);
        }
      }
      lacc4[w*64 + l] = acc;
      __syncthreads();
      if (w == 0){
        f32x4 rd = lacc4[l];
        #pragma unroll
        for (int w2=1; w2<8; ++w2) rd += lacc4[w2*64 + l];
        #pragma unroll
        for (int r=0;r<4;++r){
          int b_ = mt4*16 + g*4 + r;
          int col = nt4*16 + c;
          u16 x = f2bf(tanhf(rd[r]));
          scu16(XCn + (long)b_*2816 + 768 + col, x);
          ATT[((long)t*64 + b_)*1024 + col] = x;
        }
      }
    }
    gsync(BAR, 256, gen);
  }
}

extern "C" void kernel_launch(void* const* d_in, const int* in_sizes, int n_in,
                              void* d_out, int out_size, void* d_ws, size_t ws_size,
                              hipStream_t stream){
  const float* enc      = (const float*)d_in[0];
  const float* W_ih     = (const float*)d_in[1];
  const float* b_ih     = (const float*)d_in[2];
  const float* W_hh     = (const float*)d_in[3];
  const float* b_hh     = (const float*)d_in[4];
  const float* W_att    = (const float*)d_in[5];
  const float* W_attvec = (const float*)d_in[6];
  const float* W_init   = (const float*)d_in[7];
  const float* b_init   = (const float*)d_in[8];
  const float* W_q2a    = (const float*)d_in[9];
  const float* b_q2a    = (const float*)d_in[10];
  const float* prod_emb = (const float*)d_in[11];
  const float* prod_bias= (const float*)d_in[12];
  const float* type_emb = (const float*)d_in[13];
  const int* prev_pid   = (const int*)d_in[14];
  const int* prev_tid   = (const int*)d_in[15];
  const int* target     = (const int*)d_in[16];
  const int* sk_lens    = (const int*)d_in[17];
  const int* src_lens   = (const int*)d_in[18];
  float* out = (float*)d_out;

  char* ws = (char*)d_ws;
  size_t o = 0;
  auto alloc = [&](size_t bytes)->char*{ char* p = ws + o; o += (bytes + 255) & ~(size_t)255; return p; };
  u16*  ENC  = (u16*)alloc((size_t)64*1024*1024*2);   // 128MB
  u16*  WC   = (u16*)alloc((size_t)4096*2816*2);      // 22.5MB
  u16*  WAVT = (u16*)alloc((size_t)1024*1024*2);
  u16*  WAVEC= (u16*)alloc((size_t)1024*2048*2);
  u16*  WQ   = (u16*)alloc((size_t)512*1024*2);
  u16*  PE   = (u16*)alloc((size_t)256*512*2);
  u16*  WINIT= (u16*)alloc((size_t)1024*1024*2);
  u16*  MEANB= (u16*)alloc((size_t)64*1024*2);
  u16*  XC   = (u16*)alloc((size_t)65*64*2816*2);     // 23.4MB
  u16*  ATT  = (u16*)alloc((size_t)64*64*1024*2);     // 8MB
  float* HWT = (float*)alloc((size_t)64*64*1024*4);   // 16MB (per-step)
  float* PMT = (float*)alloc((size_t)64*256*4);
  float* PLT = (float*)alloc((size_t)64*256*4);
  float* CTXPT=(float*)alloc((size_t)64*256*1024*4);  // 64MB (per-step)
  u16*  Q    = (u16*)alloc((size_t)4096*512*2);
  float* LG  = (float*)alloc((size_t)4096*256*4);
  int*  BAR  = (int*)alloc(512);
  (void)ws_size; (void)in_sizes; (void)n_in; (void)out_size;  // needs ws >= ~300MB

  hipMemsetAsync(XC, 0, (size_t)64*2816*2, stream);   // XC[0]: embeds+att zero; h by init GEMM
  hipMemsetAsync(BAR, 0, 512, stream);

  k_cast<<<32768,256,0,stream>>>(enc, ENC, (long)64*1024*1024);
  k_cast<<<1024,256,0,stream>>>(W_attvec, WAVEC, (long)1024*2048);
  k_cast<<<256,256,0,stream>>>(W_q2a, WQ, (long)512*1024);
  k_cast<<<64,256,0,stream>>>(prod_emb, PE, (long)256*512);
  k_cast<<<512,256,0,stream>>>(W_init, WINIT, (long)1024*1024);
  k_build_wc<<<5632,256,0,stream>>>(W_ih, W_hh, WC);
  k_wattT<<<4096,256,0,stream>>>(W_att, WAVT);
  k_mean<<<dim3(64,4),256,0,stream>>>(ENC, MEANB);
  k_gemm<2><<<dim3(64,1),256,0,stream>>>(MEANB, 1024L, WINIT, 1024, b_init,
                                         nullptr, 0L, XC + 1792, 2816L);
  k_embed<<<4096,256,0,stream>>>(prod_emb, type_emb, prev_pid, prev_tid, sk_lens, XC);

  k_decoder<<<256,512,0,stream>>>(ENC, WC, WAVT, WAVEC, b_ih, b_hh,
                                  XC, ATT, HWT, PMT, PLT, CTXPT, src_lens, BAR);

  k_gemm<2><<<dim3(32,64),256,0,stream>>>(ATT, 1024L, WQ, 1024, b_q2a,
                                          nullptr, 0L, Q, 512L);
  k_gemm<3><<<dim3(16,64),256,0,stream>>>(Q, 512L, PE, 512, prod_bias,
                                          LG, 256L, nullptr, 0L);
  k_loss<<<64,256,0,stream>>>(LG, target, sk_lens, out);
}

// Round 5
// 4481.969 us; speedup vs baseline: 6.1945x; 1.0852x over previous
//
#include <hip/hip_runtime.h>
#include <hip/hip_bf16.h>

typedef unsigned short u16;
typedef unsigned int u32;
typedef unsigned long long u64;
typedef __attribute__((ext_vector_type(8))) short short8;
typedef __attribute__((ext_vector_type(8))) u16 ushort8;
typedef __attribute__((ext_vector_type(4))) u16 ushort4v;
typedef __attribute__((ext_vector_type(4))) float f32x4;

__device__ __forceinline__ float bf2f(u16 x){ u32 u=((u32)x)<<16; return __builtin_bit_cast(float,u); }
__device__ __forceinline__ u16 f2bf(float f){ u32 u=__builtin_bit_cast(u32,f); u32 r=(u+0x7fffu+((u>>16)&1u))>>16; return (u16)r; }
__device__ __forceinline__ float sigf(float x){ return 1.f/(1.f+__expf(-x)); }

// coherent STORES only (write-through past L2). Loads are plain; correctness
// from first-touch-after-write (time-indexed buffers).
__device__ __forceinline__ void scf(float* p, float v){
  __hip_atomic_store(p, v, __ATOMIC_RELAXED, __HIP_MEMORY_SCOPE_AGENT);
}
__device__ __forceinline__ void scu16(u16* p, u16 v){
  __hip_atomic_store(p, v, __ATOMIC_RELAXED, __HIP_MEMORY_SCOPE_AGENT);
}

// ---------------- prologue kernels ----------------

__global__ __launch_bounds__(256) void k_cast(const float* __restrict__ s, u16* __restrict__ d, long n){
  long i = ((long)blockIdx.x*256 + threadIdx.x)*8;
  if (i >= n) return;
  float4 a = *(const float4*)(s+i);
  float4 b = *(const float4*)(s+i+4);
  ushort8 o;
  o[0]=f2bf(a.x); o[1]=f2bf(a.y); o[2]=f2bf(a.z); o[3]=f2bf(a.w);
  o[4]=f2bf(b.x); o[5]=f2bf(b.y); o[6]=f2bf(b.z); o[7]=f2bf(b.w);
  *(ushort8*)(d+i) = o;
}

// Reordered combined weights. x-layout: [a_e(0..511) | t_e(512..767) | att(768..1791) | h(1792..2815)]
__global__ __launch_bounds__(256) void k_build_wc(const float* __restrict__ Wih, const float* __restrict__ Whh,
                                                  u16* __restrict__ WC){
  long i8 = (long)blockIdx.x*256 + threadIdx.x;           // 4096*352
  if (i8 >= (long)4096*352) return;
  int j = (int)(i8/352); int kk = (int)(i8%352)*8;
  const float* src;
  if (kk < 512)        src = Wih + (long)j*1792 + kk;
  else if (kk < 768)   src = Wih + (long)j*1792 + (kk+1024);
  else if (kk < 1792)  src = Wih + (long)j*1792 + (kk-256);
  else                 src = Whh + (long)j*1024 + (kk-1792);
  u16* dst = WC + (long)j*2816 + kk;
  ushort8 o;
  #pragma unroll
  for (int q=0;q<8;++q) o[q] = f2bf(src[q]);
  *(ushort8*)dst = o;
}

__global__ __launch_bounds__(256) void k_wattT(const float* __restrict__ Wa, u16* __restrict__ WT){
  int id = blockIdx.x*256 + threadIdx.x;                  // 1M
  int m = id >> 10, k = id & 1023;
  WT[(long)m*1024 + k] = f2bf(Wa[(long)k*1024 + m]);
}

__global__ __launch_bounds__(256) void k_mean(const u16* __restrict__ ENC, u16* __restrict__ MEANB){
  int b = blockIdx.x, h = blockIdx.y*256 + threadIdx.x;
  const u16* p = ENC + ((long)b<<20) + h;
  float s = 0.f;
  for (int ss=0; ss<1024; ++ss) s += bf2f(p[(long)ss<<10]);
  MEANB[b*1024 + h] = f2bf(s * (1.f/1024.f));
}

__global__ __launch_bounds__(256) void k_embed(const float* __restrict__ pemb, const float* __restrict__ temb,
      const int* __restrict__ pid, const int* __restrict__ tid_, const int* __restrict__ slen,
      u16* __restrict__ XC){
  int t = blockIdx.x >> 6, b = blockIdx.x & 63;
  bool valid = (t>0) && (t < slen[b]);
  int pi = pid[b*64 + t], ti = tid_[b*64 + t];
  u16* dst = XC + (long)blockIdx.x*2816;
  for (int kk = threadIdx.x; kk < 768; kk += 256){
    float v = 0.f;
    if (valid) v = (kk<512) ? pemb[(long)pi*512 + kk] : temb[(long)ti*256 + (kk-512)];
    dst[kk] = f2bf(v);
  }
}

// generic small GEMM: out = A[M x K] @ W[N x K]^T (block: 64 rows x 16 cols, 4 waves)
template<int MODE>
__global__ __launch_bounds__(256) void k_gemm(const u16* __restrict__ A, long lda,
      const u16* __restrict__ W, int K, const float* __restrict__ bias,
      float* __restrict__ OF, long ldo, u16* __restrict__ OB1, long ldb1){
  int l = threadIdx.x & 63, w = threadIdx.x >> 6;
  int c = l & 15, g = l >> 4;
  int n0 = blockIdx.x*16, m0 = blockIdx.y*64;
  const u16* ap = A + (long)(m0 + w*16 + c)*lda + g*8;
  const u16* bp = W + (long)(n0 + c)*K + g*8;
  f32x4 acc = {0.f,0.f,0.f,0.f};
  int kit = K >> 5;
  #pragma unroll 4
  for (int kb=0; kb<kit; ++kb){
    short8 av = *(const short8*)(ap + kb*32);
    short8 bv = *(const short8*)(bp + kb*32);
    acc = __builtin_amdgcn_mfma_f32_16x16x32_bf16(av, bv, acc, 0, 0, 0);
  }
  #pragma unroll
  for (int r=0;r<4;++r){
    int row = m0 + w*16 + g*4 + r;
    int col = n0 + c;
    float v = acc[r];
    if (MODE==2){ OB1[(long)row*ldb1 + col] = f2bf(tanhf(v + bias[col])); }
    if (MODE==3){ OF[(long)row*ldo + col] = v + bias[col]; }
  }
}

__global__ __launch_bounds__(256) void k_loss(const float* __restrict__ LG, const int* __restrict__ tgt,
      const int* __restrict__ slen, float* __restrict__ out){
  int b = blockIdx.x;
  int w = threadIdx.x >> 6, l = threadIdx.x & 63;
  int len = slen[b];
  float accum = 0.f;
  for (int t = w; t < 64; t += 4){
    if (t >= len) continue;
    const float* lp = LG + ((long)(t*64 + b))*256;
    float v0=lp[l], v1=lp[l+64], v2=lp[l+128], v3=lp[l+192];
    float mx = fmaxf(fmaxf(v0,v1), fmaxf(v2,v3));
    #pragma unroll
    for (int off=32; off; off>>=1) mx = fmaxf(mx, __shfl_xor(mx, off));
    float s = __expf(v0-mx)+__expf(v1-mx)+__expf(v2-mx)+__expf(v3-mx);
    #pragma unroll
    for (int off=32; off; off>>=1) s += __shfl_xor(s, off);
    float ltg = lp[tgt[b*64 + t]];
    float p = __expf(ltg - mx)/s;
    accum += logf(p + 1e-8f);
  }
  __shared__ float sm[4];
  if (l == 0) sm[w] = accum;
  __syncthreads();
  if (threadIdx.x == 0) out[b] = sm[0]+sm[1]+sm[2]+sm[3];
}

// ---------------- persistent decoder (1024 threads, 16 waves) ----------------
// Hierarchical fence-free barrier: 16 padded group counters + master.
__device__ __forceinline__ void gsync(int* __restrict__ bar, int& gen){
  gen += 1;
  __syncthreads();
  if (threadIdx.x == 0){
    int grp = blockIdx.x & 15;
    int prev = __hip_atomic_fetch_add(bar + grp*64, 1, __ATOMIC_RELAXED, __HIP_MEMORY_SCOPE_AGENT);
    if (prev == gen*16 - 1)
      __hip_atomic_fetch_add(bar + 1024, 1, __ATOMIC_RELAXED, __HIP_MEMORY_SCOPE_AGENT);
    while (__hip_atomic_load(bar + 1024, __ATOMIC_RELAXED, __HIP_MEMORY_SCOPE_AGENT) < gen*16)
      __builtin_amdgcn_s_sleep(1);
  }
  __syncthreads();
}

__global__ __launch_bounds__(1024,1) void k_decoder(
      const u16* __restrict__ ENC, const u16* __restrict__ WC,
      const u16* __restrict__ WAVT, const u16* __restrict__ WAVEC,
      const float* __restrict__ bih, const float* __restrict__ bhh,
      u16* __restrict__ XC, u16* __restrict__ ATT,
      float* __restrict__ HWT, float* __restrict__ PMT, float* __restrict__ PLT,
      float* __restrict__ CTXPT, const int* __restrict__ src_lens,
      int* __restrict__ BAR){
  const int tid = threadIdx.x;
  const int w = tid >> 6, l = tid & 63, c = l & 15, g = l >> 4;
  const int bx = blockIdx.x;
  int gen = 0;

  __shared__ float smem[12320];                 // 48.1KB, phase-aliased
  f32x4* lacc  = (f32x4*)smem;                  // P1/P2: [16][64] f32x4 (16KB)
  float* s_ctx = smem;                          // P3: [8][1024] (32KB)
  float* s_mx  = smem + 12288;                  // [16]
  float* s_ls  = smem + 12304;                  // [16]
  u16*   ldsc  = (u16*)smem;                    // P4: [16][1024] bf16 (32KB)
  f32x4* lacc4 = (f32x4*)(smem + 8192);         // P4: [16][64] f32x4 (16KB)

  // P1 constants: block = 4 n-cols x 4 gates; waves: mt = w&3 (16 b rows), kh = w>>2 (K quarter)
  const int n0 = bx << 2;
  const int jrow = n0 + (c & 3) + ((c >> 2) << 10);
  const float biasj = bih[jrow] + bhh[jrow];
  const int kh = w >> 2, mt = w & 3;
  const int lbase = l & 0x33;
  float creg[4] = {0.f,0.f,0.f,0.f};            // c-state in registers (waves 0-3)
  // P2 constants: block = mt2(16 b) x nt2(16 cols); 16 waves split K=1024
  const int mt2 = bx & 3, nt2 = bx >> 2;
  // P3 constants: block = b x s-chunk
  const int b3 = bx >> 2, p3 = bx & 3;
  int len = src_lens[b3]; if (len < 1) len = 1; if (len > 1024) len = 1024;
  const int chunk = (len + 3) >> 2;
  const int s0 = p3*chunk;
  const int s1 = (s0 + chunk < len) ? (s0 + chunk) : len;
  // P4 constants
  const int mt4 = bx & 3, nt4 = bx >> 2;
  const int b16 = tid >> 6, lane64 = tid & 63;

  for (int t = 0; t < 64; ++t){
    const u16* XCt = XC + (size_t)t*64*2816;
    u16* XCn = XC + (size_t)(t+1)*64*2816;
    const u16* Hcur = XCn + 1792;
    float* HW   = HWT  + (size_t)t*64*1024;
    float* PM   = PMT  + (size_t)t*256;
    float* PL   = PLT  + (size_t)t*256;
    float* CTXP = CTXPT + (size_t)t*256*1024;

    // ---- P1: gates GEMM (split-K x4) + LSTM pointwise; h -> XCn ----
    {
      const u16* ap = XCt + (long)(mt*16 + c)*2816 + kh*704 + g*8;
      const u16* bp = WC  + (long)jrow*2816 + kh*704 + g*8;
      f32x4 acc = {0.f,0.f,0.f,0.f};
      #pragma unroll 11
      for (int kb=0; kb<22; ++kb){
        short8 av = *(const short8*)(ap + kb*32);
        short8 bv = *(const short8*)(bp + kb*32);
        acc = __builtin_amdgcn_mfma_f32_16x16x32_bf16(av, bv, acc, 0, 0, 0);
      }
      lacc[w*64 + l] = acc;
      __syncthreads();
      if (w < 4){
        f32x4 a0 = lacc[w*64 + l];
        f32x4 a1 = lacc[(w+4)*64 + l];
        f32x4 a2 = lacc[(w+8)*64 + l];
        f32x4 a3 = lacc[(w+12)*64 + l];
        #pragma unroll
        for (int r=0;r<4;++r){
          float val = a0[r] + a1[r] + a2[r] + a3[r] + biasj;
          float iv = __shfl(val, lbase);
          float fv = __shfl(val, lbase+4);
          float gv = __shfl(val, lbase+8);
          float ov = __shfl(val, lbase+12);
          if ((l & 12) == 0){
            float cn = sigf(fv)*creg[r] + sigf(iv)*tanhf(gv);
            float hn = sigf(ov)*tanhf(cn);
            creg[r] = cn;
            int b = w*16 + g*4 + r;
            int n = n0 + (l & 3);
            scu16(XCn + (long)b*2816 + 1792 + n, f2bf(hn));
          }
        }
      }
    }
    gsync(BAR, gen);

    // ---- P2: HW = h @ W_att^T (16-way split-K, LDS reduce) ----
    {
      const u16* ap = Hcur + (long)(mt2*16 + c)*2816 + w*64 + g*8;
      const u16* bp = WAVT + (long)(nt2*16 + c)*1024 + w*64 + g*8;
      f32x4 acc = {0.f,0.f,0.f,0.f};
      #pragma unroll
      for (int kb=0; kb<2; ++kb){
        short8 av = *(const short8*)(ap + kb*32);
        short8 bv = *(const short8*)(bp + kb*32);
        acc = __builtin_amdgcn_mfma_f32_16x16x32_bf16(av, bv, acc, 0, 0, 0);
      }
      lacc[w*64 + l] = acc;
      __syncthreads();
      if (w == 0){
        f32x4 rd = lacc[l];
        #pragma unroll
        for (int w2=1; w2<16; ++w2) rd += lacc[w2*64 + l];
        #pragma unroll
        for (int r=0;r<4;++r)
          scf(HW + (long)(mt2*16 + g*4 + r)*1024 + nt2*16 + c, rd[r]);
      }
    }
    gsync(BAR, gen);

    // ---- P3: attention partials; 16 waves x 2 adjacent rows, SW-pipelined ----
    {
      float hw[16], ctx[16];
      const float* hwp = HW + b3*1024 + l*16;
      #pragma unroll
      for (int jj=0;jj<4;++jj){
        float4 v = *(const float4*)(hwp + jj*4);
        hw[4*jj]=v.x; hw[4*jj+1]=v.y; hw[4*jj+2]=v.z; hw[4*jj+3]=v.w;
      }
      #pragma unroll
      for (int jj=0;jj<16;++jj) ctx[jj]=0.f;
      float m = -INFINITY, lsum = 0.f;
      const u16* encb = ENC + (((long)b3)<<20);
      const int sA0 = s0 + 2*w;
      uint4 ca0,ca1,cb0,cb1;
      {
        int rA = (sA0   < s1) ? sA0   : s0;
        int rB = (sA0+1 < s1) ? sA0+1 : s0;
        const u16* pA = encb + ((long)rA<<10) + l*16;
        const u16* pB = encb + ((long)rB<<10) + l*16;
        ca0 = *(const uint4*)pA; ca1 = *(const uint4*)(pA+8);
        cb0 = *(const uint4*)pB; cb1 = *(const uint4*)(pB+8);
      }
      for (int s = sA0; s < s1; s += 32){
        int sn = s + 32;
        int rA = (sn   < s1) ? sn   : s0;
        int rB = (sn+1 < s1) ? sn+1 : s0;
        const u16* pA = encb + ((long)rA<<10) + l*16;
        const u16* pB = encb + ((long)rB<<10) + l*16;
        uint4 na0 = *(const uint4*)pA; uint4 na1 = *(const uint4*)(pA+8);
        uint4 nb0 = *(const uint4*)pB; uint4 nb1 = *(const uint4*)(pB+8);
        float eA[16], eB[16];
        #pragma unroll
        for (int jj=0;jj<4;++jj){
          u32 xa0=((const u32*)&ca0)[jj], xa1=((const u32*)&ca1)[jj];
          u32 xb0=((const u32*)&cb0)[jj], xb1=((const u32*)&cb1)[jj];
          eA[2*jj]   = bf2f((u16)(xa0&0xffff)); eA[2*jj+1]   = bf2f((u16)(xa0>>16));
          eA[8+2*jj] = bf2f((u16)(xa1&0xffff)); eA[8+2*jj+1] = bf2f((u16)(xa1>>16));
          eB[2*jj]   = bf2f((u16)(xb0&0xffff)); eB[2*jj+1]   = bf2f((u16)(xb0>>16));
          eB[8+2*jj] = bf2f((u16)(xb1&0xffff)); eB[8+2*jj+1] = bf2f((u16)(xb1>>16));
        }
        float scA = 0.f, scB = 0.f;
        #pragma unroll
        for (int jj=0;jj<16;++jj){ scA += eA[jj]*hw[jj]; scB += eB[jj]*hw[jj]; }
        #pragma unroll
        for (int off=32; off; off>>=1){
          scA += __shfl_xor(scA, off);
          scB += __shfl_xor(scB, off);
        }
        if (s+1 >= s1) scB = -INFINITY;
        float nm = fmaxf(m, fmaxf(scA, scB));
        float corr = __expf(m - nm);
        float peA = __expf(scA - nm);
        float peB = __expf(scB - nm);
        lsum = lsum*corr + peA + peB;
        #pragma unroll
        for (int jj=0;jj<16;++jj) ctx[jj] = ctx[jj]*corr + peA*eA[jj] + peB*eB[jj];
        m = nm;
        ca0=na0; ca1=na1; cb0=nb0; cb1=nb1;
      }
      if (l == 0){ s_mx[w] = m; s_ls[w] = lsum; }
      __syncthreads();
      float M16 = s_mx[0];
      #pragma unroll
      for (int q=1;q<16;++q) M16 = fmaxf(M16, s_mx[q]);
      float L = 0.f;
      #pragma unroll
      for (int q=0;q<16;++q){
        float wq = (s_mx[q]==-INFINITY)?0.f:__expf(s_mx[q]-M16);
        L += wq * s_ls[q];
      }
      float wei = (m == -INFINITY) ? 0.f : __expf(m - M16);
      if (w < 8){
        #pragma unroll
        for (int jj=0;jj<16;++jj) s_ctx[w*1024 + l*16 + jj] = wei*ctx[jj];
      }
      __syncthreads();
      if (w >= 8){
        #pragma unroll
        for (int jj=0;jj<16;++jj) s_ctx[(w-8)*1024 + l*16 + jj] += wei*ctx[jj];
      }
      __syncthreads();
      {
        float v = 0.f;
        #pragma unroll
        for (int p=0;p<8;++p) v += s_ctx[p*1024 + tid];
        scf(CTXP + (long)bx*1024 + tid, v);
      }
      if (tid == 0){ scf(PM + bx, M16); scf(PL + bx, L); }
    }
    gsync(BAR, gen);

    // ---- P4: ctx combine (16 b -> LDS swz) + att = tanh([h|ctx]@W_attvec^T) ----
    {
      int b = mt4*16 + b16;
      const float* pmb = PM + b*4;
      const float* plb = PL + b*4;
      float m0=pmb[0], m1=pmb[1], m2=pmb[2], m3=pmb[3];
      float M = fmaxf(fmaxf(m0,m1), fmaxf(m2,m3));
      float w0 = (m0==-INFINITY)?0.f:__expf(m0-M);
      float w1 = (m1==-INFINITY)?0.f:__expf(m1-M);
      float w2 = (m2==-INFINITY)?0.f:__expf(m2-M);
      float w3 = (m3==-INFINITY)?0.f:__expf(m3-M);
      float L = w0*plb[0] + w1*plb[1] + w2*plb[2] + w3*plb[3];
      float inv = (L > 0.f) ? 1.f/L : 0.f;
      const float* c0 = CTXP + (long)(b*4+0)*1024;
      const float* c1 = CTXP + (long)(b*4+1)*1024;
      const float* c2 = CTXP + (long)(b*4+2)*1024;
      const float* c3 = CTXP + (long)(b*4+3)*1024;
      const int swz = (b16 & 7) << 3;
      #pragma unroll
      for (int q=0;q<4;++q){
        int mcol = (lane64 + q*64)*4;
        float4 a0 = *(const float4*)(c0 + mcol);
        float4 a1 = *(const float4*)(c1 + mcol);
        float4 a2 = *(const float4*)(c2 + mcol);
        float4 a3 = *(const float4*)(c3 + mcol);
        ushort4v o;
        o[0] = f2bf((w0*a0.x + w1*a1.x + w2*a2.x + w3*a3.x) * inv);
        o[1] = f2bf((w0*a0.y + w1*a1.y + w2*a2.y + w3*a3.y) * inv);
        o[2] = f2bf((w0*a0.z + w1*a1.z + w2*a2.z + w3*a3.z) * inv);
        o[3] = f2bf((w0*a0.w + w1*a1.w + w2*a2.w + w3*a3.w) * inv);
        *(ushort4v*)(ldsc + ((b16*1024 + mcol) ^ swz)) = o;
      }
      __syncthreads();
      f32x4 acc = {0.f,0.f,0.f,0.f};
      const int koff = (w < 8) ? w*128 : 1024 + (w-8)*128;
      const u16* bp = WAVEC + (long)(nt4*16 + c)*2048 + koff + g*8;
      if (w < 8){
        const u16* ap = Hcur + (long)(mt4*16 + c)*2816 + w*128 + g*8;
        #pragma unroll
        for (int kb=0; kb<4; ++kb){
          short8 av = *(const short8*)(ap + kb*32);
          short8 bv = *(const short8*)(bp + kb*32);
          acc = __builtin_amdgcn_mfma_f32_16x16x32_bf16(av, bv, acc, 0, 0, 0);
        }
      } else {
        const int cswz = (c & 7) << 3;
        const int kbase = c*1024 + (w-8)*128 + g*8;
        #pragma unroll
        for (int kb=0; kb<4; ++kb){
          short8 av = *(const short8*)(ldsc + ((kbase + kb*32) ^ cswz));
          short8 bv = *(const short8*)(bp + kb*32);
          acc = __builtin_amdgcn_mfma_f32_16x16x32_bf16(av, bv, acc, 0, 0, 0);
        }
      }
      lacc4[w*64 + l] = acc;
      __syncthreads();
      if (w == 0){
        f32x4 rd = lacc4[l];
        #pragma unroll
        for (int w2=1; w2<16; ++w2) rd += lacc4[w2*64 + l];
        #pragma unroll
        for (int r=0;r<4;++r){
          int b_ = mt4*16 + g*4 + r;
          int col = nt4*16 + c;
          u16 x = f2bf(tanhf(rd[r]));
          scu16(XCn + (long)b_*2816 + 768 + col, x);
          ATT[((long)t*64 + b_)*1024 + col] = x;
        }
      }
    }
    gsync(BAR, gen);
  }
}

extern "C" void kernel_launch(void* const* d_in, const int* in_sizes, int n_in,
                              void* d_out, int out_size, void* d_ws, size_t ws_size,
                              hipStream_t stream){
  const float* enc      = (const float*)d_in[0];
  const float* W_ih     = (const float*)d_in[1];
  const float* b_ih     = (const float*)d_in[2];
  const float* W_hh     = (const float*)d_in[3];
  const float* b_hh     = (const float*)d_in[4];
  const float* W_att    = (const float*)d_in[5];
  const float* W_attvec = (const float*)d_in[6];
  const float* W_init   = (const float*)d_in[7];
  const float* b_init   = (const float*)d_in[8];
  const float* W_q2a    = (const float*)d_in[9];
  const float* b_q2a    = (const float*)d_in[10];
  const float* prod_emb = (const float*)d_in[11];
  const float* prod_bias= (const float*)d_in[12];
  const float* type_emb = (const float*)d_in[13];
  const int* prev_pid   = (const int*)d_in[14];
  const int* prev_tid   = (const int*)d_in[15];
  const int* target     = (const int*)d_in[16];
  const int* sk_lens    = (const int*)d_in[17];
  const int* src_lens   = (const int*)d_in[18];
  float* out = (float*)d_out;

  char* ws = (char*)d_ws;
  size_t o = 0;
  auto alloc = [&](size_t bytes)->char*{ char* p = ws + o; o += (bytes + 255) & ~(size_t)255; return p; };
  u16*  ENC  = (u16*)alloc((size_t)64*1024*1024*2);   // 128MB
  u16*  WC   = (u16*)alloc((size_t)4096*2816*2);      // 22.5MB
  u16*  WAVT = (u16*)alloc((size_t)1024*1024*2);
  u16*  WAVEC= (u16*)alloc((size_t)1024*2048*2);
  u16*  WQ   = (u16*)alloc((size_t)512*1024*2);
  u16*  PE   = (u16*)alloc((size_t)256*512*2);
  u16*  WINIT= (u16*)alloc((size_t)1024*1024*2);
  u16*  MEANB= (u16*)alloc((size_t)64*1024*2);
  u16*  XC   = (u16*)alloc((size_t)65*64*2816*2);     // 23.4MB
  u16*  ATT  = (u16*)alloc((size_t)64*64*1024*2);     // 8MB
  float* HWT = (float*)alloc((size_t)64*64*1024*4);   // 16MB (per-step)
  float* PMT = (float*)alloc((size_t)64*256*4);
  float* PLT = (float*)alloc((size_t)64*256*4);
  float* CTXPT=(float*)alloc((size_t)64*256*1024*4);  // 64MB (per-step)
  u16*  Q    = (u16*)alloc((size_t)4096*512*2);
  float* LG  = (float*)alloc((size_t)4096*256*4);
  int*  BAR  = (int*)alloc(8192);
  (void)ws_size; (void)in_sizes; (void)n_in; (void)out_size;  // needs ws >= ~300MB

  hipMemsetAsync(XC, 0, (size_t)64*2816*2, stream);   // XC[0]: embeds+att zero; h by init GEMM
  hipMemsetAsync(BAR, 0, 8192, stream);

  k_cast<<<32768,256,0,stream>>>(enc, ENC, (long)64*1024*1024);
  k_cast<<<1024,256,0,stream>>>(W_attvec, WAVEC, (long)1024*2048);
  k_cast<<<256,256,0,stream>>>(W_q2a, WQ, (long)512*1024);
  k_cast<<<64,256,0,stream>>>(prod_emb, PE, (long)256*512);
  k_cast<<<512,256,0,stream>>>(W_init, WINIT, (long)1024*1024);
  k_build_wc<<<5632,256,0,stream>>>(W_ih, W_hh, WC);
  k_wattT<<<4096,256,0,stream>>>(W_att, WAVT);
  k_mean<<<dim3(64,4),256,0,stream>>>(ENC, MEANB);
  k_gemm<2><<<dim3(64,1),256,0,stream>>>(MEANB, 1024L, WINIT, 1024, b_init,
                                         nullptr, 0L, XC + 1792, 2816L);
  k_embed<<<4096,256,0,stream>>>(prod_emb, type_emb, prev_pid, prev_tid, sk_lens, XC);

  k_decoder<<<256,1024,0,stream>>>(ENC, WC, WAVT, WAVEC, b_ih, b_hh,
                                   XC, ATT, HWT, PMT, PLT, CTXPT, src_lens, BAR);

  k_gemm<2><<<dim3(32,64),256,0,stream>>>(ATT, 1024L, WQ, 1024, b_q2a,
                                          nullptr, 0L, Q, 512L);
  k_gemm<3><<<dim3(16,64),256,0,stream>>>(Q, 512L, PE, 512, prod_bias,
                                          LG, 256L, nullptr, 0L);
  k_loss<<<64,256,0,stream>>>(LG, target, sk_lens, out);
}